// Round 6
// baseline (349.600 us; speedup 1.0000x reference)
//
#include <hip/hip_runtime.h>
#include <hip/hip_bf16.h>
#include <math.h>

#define B_ 32
#define S_ 128
#define L_ 1024
#define D_ 1024

typedef unsigned short u16;
typedef __attribute__((ext_vector_type(8))) __bf16 bf16x8;
typedef __attribute__((ext_vector_type(4))) float f32x4;

__device__ __forceinline__ float bf2f(u16 u) {
    return __uint_as_float(((unsigned)u) << 16);
}
__device__ __forceinline__ u16 f2bf(float f) {
    unsigned u = __float_as_uint(f);
    u += 0x7FFF + ((u >> 16) & 1);
    return (u16)(u >> 16);
}
__device__ __forceinline__ float gelu_tanh(float x) {
    float x3 = x * x * x;
    float t = tanhf(0.7978845608028654f * (x + 0.044715f * x3));
    return 0.5f * x * (1.0f + t);
}
__device__ __forceinline__ float sigmoidf(float x) {
    return 1.0f / (1.0f + expf(-x));
}
__device__ __forceinline__ void gld16(const void* g, void* l) {
    __builtin_amdgcn_global_load_lds((const __attribute__((address_space(1))) void*)g,
                                     (__attribute__((address_space(3))) void*)l, 16, 0, 0);
}

// ---------------- K0: S4D SSM kernel, writes Kt[j][d] (j-major, 64x1024) ----
__global__ __launch_bounds__(256) void k_ssmk(
        const float* __restrict__ log_dt, const float* __restrict__ Alr,
        const float* __restrict__ Aim, const float* __restrict__ Cr,
        const float* __restrict__ Ci, float* __restrict__ Kt) {
    int tid = blockIdx.x * 256 + threadIdx.x;
    int d = tid & (D_ - 1);
    int j = tid >> 10;
    float dt = expf(log_dt[d]);
    float acc = 0.f;
    #pragma unroll
    for (int n = 0; n < 4; ++n) {
        float ar = -expf(Alr[d * 4 + n]);
        float ai = Aim[d * 4 + n];
        float wr = ar * dt, wi = ai * dt;
        float ew = expf(wr);
        float sw, cw; sincosf(wi, &sw, &cw);
        float ur = ew * cw - 1.0f, ui = ew * sw;
        float inv = 1.0f / (ar * ar + ai * ai);
        float bdr = (ur * ar + ui * ai) * inv;
        float bdi = (ui * ar - ur * ai) * inv;
        float cr = Cr[d * 4 + n], ci = Ci[d * 4 + n];
        float cbr = cr * bdr - ci * bdi;
        float cbi = cr * bdi + ci * bdr;
        float ej = expf(wr * (float)j);
        float sj, cj; sincosf(wi * (float)j, &sj, &cj);
        acc += 2.0f * ej * (cbr * cj - cbi * sj);
    }
    Kt[j * D_ + d] = acc;
}

// ---------------- transpose+cast: src f32 [R][C] -> dst bf16 [C][R], batched z
__global__ __launch_bounds__(256) void k_tcast(
        const float* __restrict__ src0, u16* __restrict__ dst0, int R, int C) {
    __shared__ float tile[64][65];
    const float* src = src0 + (size_t)blockIdx.z * R * C;
    u16* dst = dst0 + (size_t)blockIdx.z * R * C;
    int c0 = blockIdx.x * 64;
    int r0 = blockIdx.y * 64;
    int t = threadIdx.x;
    #pragma unroll
    for (int p = 0; p < 4; ++p) {
        int fid = p * 256 + t;
        int rr = fid >> 4, cc = (fid & 15) * 4;
        float4 v = *(const float4*)&src[(size_t)(r0 + rr) * C + c0 + cc];
        tile[rr][cc + 0] = v.x; tile[rr][cc + 1] = v.y;
        tile[rr][cc + 2] = v.z; tile[rr][cc + 3] = v.w;
    }
    __syncthreads();
    #pragma unroll
    for (int p = 0; p < 4; ++p) {
        int fid = p * 256 + t;
        int rr = fid >> 4, cc = (fid & 15) * 4;
        ushort4 o;
        o.x = f2bf(tile[cc + 0][rr]);
        o.y = f2bf(tile[cc + 1][rr]);
        o.z = f2bf(tile[cc + 2][rr]);
        o.w = f2bf(tile[cc + 3][rr]);
        *(ushort4*)&dst[(size_t)(c0 + rr) * R + r0 + cc] = o;
    }
}

// ---------------- K1: encoder MFMA: hb[m][e] = xb[m][:]·WeT[e][:] + be[e] ---
__global__ __launch_bounds__(256) void k_enc_mfma(
        const u16* __restrict__ xb, const u16* __restrict__ WeT,
        const float* __restrict__ be, u16* __restrict__ hb) {
    __shared__ u16 As[128 * 128];
    __shared__ u16 Bs[128 * 128];
    int t = threadIdx.x;
    int lane = t & 63, wid = t >> 6;
    int wr = wid & 1, wc = wid >> 1;
    int orig = blockIdx.x;
    int wgid = (orig & 7) * 256 + (orig >> 3);
    int m0 = (wgid >> 3) * 128;
    int e0 = (wgid & 7) * 128;

    #pragma unroll
    for (int c = 0; c < 8; ++c) {
        int ch = wid * 8 + c;
        int r = ch * 4 + (lane >> 4);
        int g = (lane & 15) ^ (r & 15);
        gld16(&xb[(size_t)(m0 + r) * 128 + g * 8], &As[ch * 512]);
        gld16(&WeT[(size_t)(e0 + r) * 128 + g * 8], &Bs[ch * 512]);
    }
    int co4[4];
    #pragma unroll
    for (int kh = 0; kh < 4; ++kh)
        co4[kh] = ((((lane >> 4) + kh * 4) ^ (lane & 15)) * 8);
    int arow[4], brow[4];
    #pragma unroll
    for (int i = 0; i < 4; ++i) arow[i] = (wr * 64 + i * 16 + (lane & 15)) * 128;
    #pragma unroll
    for (int q = 0; q < 4; ++q) brow[q] = (wc * 64 + q * 16 + (lane & 15)) * 128;

    __syncthreads();
    f32x4 acc[4][4] = {};
    #pragma unroll
    for (int kh = 0; kh < 4; ++kh) {
        bf16x8 af[4], bfr[4];
        #pragma unroll
        for (int i = 0; i < 4; ++i) af[i] = *(const bf16x8*)&As[arow[i] + co4[kh]];
        #pragma unroll
        for (int q = 0; q < 4; ++q) bfr[q] = *(const bf16x8*)&Bs[brow[q] + co4[kh]];
        __builtin_amdgcn_s_setprio(1);
        #pragma unroll
        for (int i = 0; i < 4; ++i)
            #pragma unroll
            for (int q = 0; q < 4; ++q)
                acc[i][q] = __builtin_amdgcn_mfma_f32_16x16x32_bf16(af[i], bfr[q], acc[i][q], 0, 0, 0);
        __builtin_amdgcn_s_setprio(0);
    }
    #pragma unroll
    for (int q = 0; q < 4; ++q) {
        int e = e0 + wc * 64 + q * 16 + (lane & 15);
        float bias = be[e];
        #pragma unroll
        for (int i = 0; i < 4; ++i) {
            #pragma unroll
            for (int r = 0; r < 4; ++r) {
                int m = m0 + wr * 64 + i * 16 + (lane >> 4) * 4 + r;
                hb[(size_t)m * 1024 + e] = f2bf(acc[i][q][r] + bias);
            }
        }
    }
}

// ---------------- K2: causal 64-tap conv + D*skip + GELU -------------------
__global__ __launch_bounds__(256) void k_conv(
        const u16* __restrict__ hb, const float* __restrict__ Kt,
        const float* __restrict__ Dv, u16* __restrict__ yg) {
    __shared__ float hs[128][64];
    int b = blockIdx.z;
    int l0 = blockIdx.y * 64;
    int d0 = blockIdx.x * 64;
    int t = threadIdx.x;
    int dl = t & 63, lg = t >> 6;
    #pragma unroll
    for (int p = 0; p < 8; ++p) {
        int fid = p * 256 + t;
        int r = fid >> 4, c4 = fid & 15;
        int l = l0 - 64 + r;
        float4 v = make_float4(0.f, 0.f, 0.f, 0.f);
        if (l >= 0) {
            ushort4 u = *(const ushort4*)&hb[((size_t)b * 1024 + l) * 1024 + d0 + c4 * 4];
            v = make_float4(bf2f(u.x), bf2f(u.y), bf2f(u.z), bf2f(u.w));
        }
        *(float4*)&hs[r][c4 * 4] = v;
    }
    float kr[64];
    #pragma unroll
    for (int j = 0; j < 64; ++j) kr[j] = Kt[j * 1024 + d0 + dl];
    float Dd = Dv[d0 + dl];
    __syncthreads();
    float acc[16] = {};
    int rbase = lg * 16 + 1;
    #pragma unroll
    for (int s = 0; s < 15; ++s) {
        float hv = hs[rbase + s][dl];
        #pragma unroll
        for (int i = 0; i <= 14; ++i)
            if (i <= s) acc[i] = fmaf(kr[i + 63 - s], hv, acc[i]);
    }
    #pragma unroll
    for (int s = 15; s < 64; ++s) {
        float hv = hs[rbase + s][dl];
        #pragma unroll
        for (int i = 0; i < 16; ++i)
            acc[i] = fmaf(kr[i + 63 - s], hv, acc[i]);
    }
    #pragma unroll
    for (int s = 64; s < 79; ++s) {
        float hv = hs[rbase + s][dl];
        #pragma unroll
        for (int i = 1; i < 16; ++i)
            if (i >= s - 63) acc[i] = fmaf(kr[i + 63 - s], hv, acc[i]);
    }
    #pragma unroll
    for (int i = 0; i < 16; ++i) {
        int l = l0 + lg * 16 + i;
        float z = hs[64 + lg * 16 + i][dl];
        float y = acc[i] + Dd * z;
        yg[((size_t)b * 1024 + l) * 1024 + d0 + dl] = f2bf(gelu_tanh(y));
    }
}

// ---------------- K3: GLU GEMM 256-tile, BK=32, quad-buffer deep pipeline --
// M=32768, N=2048 (128 pairs/tile), K=1024 -> 32 K-tiles. 8 waves.
// LDS: 4 bufs x (A 16KB + B 16KB) = 128 KB. Stage depth: 3 tiles ahead.
// Per tile: vmcnt(8) + 1 barrier; 2 phases x 16 MFMA; stages for t+3 between.
// Swizzle (BK=32, 4 slots/row): slot = G ^ ((row>>1)&3)  -> b128 conflict-free.
__global__ __launch_bounds__(512, 2) void k_glu256(
        const u16* __restrict__ yg, const u16* __restrict__ WgT,
        const float* __restrict__ bg, u16* __restrict__ hb) {
    __shared__ u16 Asm[4][8192];   // [buf][256 rows][32 k]
    __shared__ u16 Bsm[4][8192];
    int t = threadIdx.x;
    int lane = t & 63, wid = t >> 6;
    int wr = wid >> 2, wc = wid & 3;

    int orig = blockIdx.x;
    int wgid = (orig & 7) * 128 + (orig >> 3);   // bijective XCD swizzle (1024%8==0)
    int m0 = (wgid >> 3) * 256;
    int p0g = (wgid & 7) * 128;

    // staging: chunk = 16 rows x 32k = 1KB; lane -> row lane>>2, slot lane&3
    int crow = lane >> 2;
    int gofs = (((lane & 3) ^ ((lane >> 3) & 3)) * 8);  // slot ^ perm(row), perm=(row>>1)&3
    int ch0 = wid * 2, ch1 = ch0 + 1;
    int rA0 = ch0 * 16 + crow, rA1 = ch1 * 16 + crow;   // rows 0..255
    int dA0 = ch0 * 512, dA1 = ch1 * 512;               // LDS elem offsets
    int gB0 = ((rA0 >> 4) & 1) * 1024 + p0g + (((rA0 >> 5) << 4) | (rA0 & 15));
    int gB1 = ((rA1 >> 4) & 1) * 1024 + p0g + (((rA1 >> 5) << 4) | (rA1 & 15));

    // fragment read offset: row = base + (lane&15), granule G = lane>>4
    int aco = (lane & 15) * 32 + (((lane >> 4) ^ (((lane & 15) >> 1) & 3)) * 8);
    int abase = wr * 128 * 32;   // + mh*2048 + i*512 + aco
    int bbase = wc * 64 * 32;    // + q*512 + aco

#define STAGE_A(T) { int k0_ = (T) * 32; u16* d_ = &Asm[(T) & 3][0]; \
    gld16(&yg[(size_t)(m0 + rA0) * 1024 + k0_ + gofs], d_ + dA0); \
    gld16(&yg[(size_t)(m0 + rA1) * 1024 + k0_ + gofs], d_ + dA1); }
#define STAGE_B(T) { int k0_ = (T) * 32; u16* d_ = &Bsm[(T) & 3][0]; \
    gld16(&WgT[(size_t)gB0 * 1024 + k0_ + gofs], d_ + dA0); \
    gld16(&WgT[(size_t)gB1 * 1024 + k0_ + gofs], d_ + dA1); }

    f32x4 acc[8][4] = {};
    bf16x8 af[4], bf[4];

    // prologue: tiles 0,1,2 (FIFO: [A0 B0][A1 B1][A2 B2] = 12 loads/thread)
    STAGE_A(0); STAGE_B(0); STAGE_A(1); STAGE_B(1); STAGE_A(2); STAGE_B(2);

#define TILE_BODY(KT, WAITN, DO_STAGE) { \
    asm volatile("s_waitcnt vmcnt(" #WAITN ")" ::: "memory"); \
    __builtin_amdgcn_s_barrier(); \
    __builtin_amdgcn_sched_barrier(0); \
    const u16* Ac_ = &Asm[(KT) & 3][0]; \
    const u16* Bc_ = &Bsm[(KT) & 3][0]; \
    _Pragma("unroll") for (int q = 0; q < 4; ++q) bf[q] = *(const bf16x8*)&Bc_[bbase + q * 512 + aco]; \
    _Pragma("unroll") for (int i = 0; i < 4; ++i) af[i] = *(const bf16x8*)&Ac_[abase + i * 512 + aco]; \
    if (DO_STAGE) STAGE_A((KT) + 3); \
    __builtin_amdgcn_s_setprio(1); \
    _Pragma("unroll") for (int i = 0; i < 4; ++i) \
        _Pragma("unroll") for (int q = 0; q < 4; ++q) \
            acc[i][q] = __builtin_amdgcn_mfma_f32_16x16x32_bf16(af[i], bf[q], acc[i][q], 0, 0, 0); \
    __builtin_amdgcn_s_setprio(0); \
    _Pragma("unroll") for (int i = 0; i < 4; ++i) af[i] = *(const bf16x8*)&Ac_[abase + 2048 + i * 512 + aco]; \
    if (DO_STAGE) STAGE_B((KT) + 3); \
    __builtin_amdgcn_s_setprio(1); \
    _Pragma("unroll") for (int i = 0; i < 4; ++i) \
        _Pragma("unroll") for (int q = 0; q < 4; ++q) \
            acc[4 + i][q] = __builtin_amdgcn_mfma_f32_16x16x32_bf16(af[i], bf[q], acc[4 + i][q], 0, 0, 0); \
    __builtin_amdgcn_s_setprio(0); }

    for (int kt = 0; kt < 29; ++kt) TILE_BODY(kt, 8, 1);
    TILE_BODY(29, 8, 0);
    TILE_BODY(30, 4, 0);
    TILE_BODY(31, 0, 0);
#undef TILE_BODY
#undef STAGE_A
#undef STAGE_B

    // epilogue: GLU activation + residual in-place
    #pragma unroll
    for (int i = 0; i < 8; ++i) {
        #pragma unroll
        for (int tt = 0; tt < 2; ++tt) {
            int col = p0g + (wc * 2 + tt) * 16 + (lane & 15);
            float b1v = bg[col];
            float b2v = bg[1024 + col];
            #pragma unroll
            for (int r = 0; r < 4; ++r) {
                int m = m0 + wr * 128 + i * 16 + (lane >> 4) * 4 + r;
                size_t idx = (size_t)m * 1024 + col;
                float g1 = acc[i][tt * 2][r] + b1v;
                float g2 = acc[i][tt * 2 + 1][r] + b2v;
                hb[idx] = f2bf(bf2f(hb[idx]) + g1 * sigmoidf(g2));
            }
        }
    }
}

// ---------------- K4: LayerNorm in-place on hb ------------------------------
__global__ __launch_bounds__(256) void k_ln(
        u16* __restrict__ hb, const float* __restrict__ gamma,
        const float* __restrict__ beta) {
    int row = blockIdx.x;
    int t = threadIdx.x;
    size_t base = (size_t)row * 1024;
    ushort4 u = *(const ushort4*)&hb[base + t * 4];
    float v0 = bf2f(u.x), v1 = bf2f(u.y), v2 = bf2f(u.z), v3 = bf2f(u.w);
    float s = v0 + v1 + v2 + v3;
    float s2 = v0 * v0 + v1 * v1 + v2 * v2 + v3 * v3;
    #pragma unroll
    for (int off = 32; off > 0; off >>= 1) {
        s += __shfl_down(s, off);
        s2 += __shfl_down(s2, off);
    }
    __shared__ float rs[4], rs2[4];
    int wid = t >> 6, lane = t & 63;
    if (lane == 0) { rs[wid] = s; rs2[wid] = s2; }
    __syncthreads();
    float ts = rs[0] + rs[1] + rs[2] + rs[3];
    float ts2 = rs2[0] + rs2[1] + rs2[2] + rs2[3];
    float mean = ts * (1.0f / 1024.0f);
    float var = ts2 * (1.0f / 1024.0f) - mean * mean;
    float rstd = rsqrtf(var + 1e-5f);
    float4 gm = *(const float4*)&gamma[t * 4];
    float4 bt = *(const float4*)&beta[t * 4];
    ushort4 o;
    o.x = f2bf((v0 - mean) * rstd * gm.x + bt.x);
    o.y = f2bf((v1 - mean) * rstd * gm.y + bt.y);
    o.z = f2bf((v2 - mean) * rstd * gm.z + bt.z);
    o.w = f2bf((v3 - mean) * rstd * gm.w + bt.w);
    *(ushort4*)&hb[base + t * 4] = o;
}

// ---------------- K5: decoder GEMM (dbuf + swizzle) + transpose store ------
__global__ __launch_bounds__(256) void k_dec_mfma(
        const u16* __restrict__ hb, const u16* __restrict__ WdT,
        const float* __restrict__ bd, float* __restrict__ out) {
    __shared__ __align__(16) char smem[65536];
    u16* As = (u16*)smem;
    u16* Bs = (u16*)(smem + 32768);
    float* Ts = (float*)smem;
    int t = threadIdx.x;
    int lane = t & 63, wid = t >> 6;
    int wr = wid & 1, wc = wid >> 1;
    int m0 = blockIdx.x * 128;
    int bb = m0 >> 10, l0 = m0 & 1023;

    int gsrc = (((lane & 7) ^ (lane >> 3)) * 8);
    int rr4[4];
    #pragma unroll
    for (int c = 0; c < 4; ++c) rr4[c] = (wid * 4 + c) * 8 + (lane >> 3);
    int co[2];
    co[0] = (((lane >> 4) + 0) ^ (lane & 7)) * 8;
    co[1] = (((lane >> 4) + 4) ^ (lane & 7)) * 8;
    int arow[4], brow[4];
    #pragma unroll
    for (int i = 0; i < 4; ++i) arow[i] = (wr * 64 + i * 16 + (lane & 15)) * 64;
    #pragma unroll
    for (int q = 0; q < 4; ++q) brow[q] = (wc * 64 + q * 16 + (lane & 15)) * 64;

    f32x4 acc[4][4] = {};
    #pragma unroll
    for (int c = 0; c < 4; ++c) {
        int ch = wid * 4 + c;
        gld16(&hb[(size_t)(m0 + rr4[c]) * 1024 + gsrc], &As[0 * 8192 + ch * 512]);
        gld16(&WdT[(size_t)rr4[c] * 1024 + gsrc], &Bs[0 * 8192 + ch * 512]);
    }
    __syncthreads();
    int cur = 0;
    for (int kt = 0; kt < 16; ++kt) {
        if (kt < 15) {
            int k0 = (kt + 1) * 64;
            #pragma unroll
            for (int c = 0; c < 4; ++c) {
                int ch = wid * 4 + c;
                gld16(&hb[(size_t)(m0 + rr4[c]) * 1024 + k0 + gsrc], &As[(cur ^ 1) * 8192 + ch * 512]);
                gld16(&WdT[(size_t)rr4[c] * 1024 + k0 + gsrc], &Bs[(cur ^ 1) * 8192 + ch * 512]);
            }
        }
        #pragma unroll
        for (int kh = 0; kh < 2; ++kh) {
            bf16x8 af[4], bfr[4];
            #pragma unroll
            for (int i = 0; i < 4; ++i) af[i] = *(const bf16x8*)&As[cur * 8192 + arow[i] + co[kh]];
            #pragma unroll
            for (int q = 0; q < 4; ++q) bfr[q] = *(const bf16x8*)&Bs[cur * 8192 + brow[q] + co[kh]];
            __builtin_amdgcn_s_setprio(1);
            #pragma unroll
            for (int i = 0; i < 4; ++i)
                #pragma unroll
                for (int q = 0; q < 4; ++q)
                    acc[i][q] = __builtin_amdgcn_mfma_f32_16x16x32_bf16(af[i], bfr[q], acc[i][q], 0, 0, 0);
            __builtin_amdgcn_s_setprio(0);
        }
        __syncthreads();
        cur ^= 1;
    }
    __syncthreads();
    #pragma unroll
    for (int ro = 0; ro < 2; ++ro) {
        if (wc == ro) {
            #pragma unroll
            for (int i = 0; i < 4; ++i)
                #pragma unroll
                for (int q = 0; q < 4; ++q) {
                    int sl = q * 16 + (lane & 15);
                    float bias = bd[ro * 64 + sl];
                    #pragma unroll
                    for (int r = 0; r < 4; ++r) {
                        int ml = wr * 64 + i * 16 + (lane >> 4) * 4 + r;
                        Ts[sl * 132 + ml] = acc[i][q][r] + bias;
                    }
                }
        }
        __syncthreads();
        #pragma unroll
        for (int p = 0; p < 8; ++p) {
            int fid = p * 256 + t;
            int sl = fid >> 5, c = (fid & 31) * 4;
            float4 v = *(const float4*)&Ts[sl * 132 + c];
            *(float4*)&out[(size_t)bb * 131072 + (size_t)(ro * 64 + sl) * 1024 + l0 + c] = v;
        }
        __syncthreads();
    }
}

extern "C" void kernel_launch(void* const* d_in, const int* in_sizes, int n_in,
                              void* d_out, int out_size, void* d_ws, size_t ws_size,
                              hipStream_t stream) {
    (void)in_sizes; (void)n_in; (void)out_size; (void)ws_size;
    const float* x   = (const float*)d_in[0];
    const float* We  = (const float*)d_in[1];
    const float* be  = (const float*)d_in[2];
    const float* ldt = (const float*)d_in[3];
    const float* Alr = (const float*)d_in[4];
    const float* Aim = (const float*)d_in[5];
    const float* Cr  = (const float*)d_in[6];
    const float* Ci  = (const float*)d_in[7];
    const float* Dv  = (const float*)d_in[8];
    const float* Wg  = (const float*)d_in[9];
    const float* bg  = (const float*)d_in[10];
    const float* gam = (const float*)d_in[11];
    const float* bet = (const float*)d_in[12];
    const float* Wd  = (const float*)d_in[13];
    const float* bd  = (const float*)d_in[14];
    float* out = (float*)d_out;

    u16* hb = (u16*)d_ws;                       // 67 MB
    u16* yg = hb + 33554432ull;                 // 67 MB
    float* Kt = (float*)(yg + 33554432ull);     // 256 KB
    u16* WgT = (u16*)(Kt + 65536);              // 4 MB
    u16* WdT = WgT + 2097152ull;                // 256 KB
    u16* WeT = WdT + 131072ull;                 // 256 KB
    u16* xb  = yg;                              // alias: xb dead before conv writes yg

    k_tcast<<<dim3(32, 16, 1), 256, 0, stream>>>(Wg, WgT, 1024, 2048);
    k_tcast<<<dim3(2, 16, 1), 256, 0, stream>>>(Wd, WdT, 1024, 128);
    k_tcast<<<dim3(16, 2, 1), 256, 0, stream>>>(We, WeT, 128, 1024);
    k_tcast<<<dim3(16, 2, 32), 256, 0, stream>>>(x, xb, 128, 1024);
    k_ssmk<<<256, 256, 0, stream>>>(ldt, Alr, Aim, Cr, Ci, Kt);
    k_enc_mfma<<<2048, 256, 0, stream>>>(xb, WeT, be, hb);
    k_conv<<<dim3(16, 16, 32), 256, 0, stream>>>(hb, Kt, Dv, yg);
    k_glu256<<<1024, 512, 0, stream>>>(yg, WgT, bg, hb);
    k_ln<<<32768, 256, 0, stream>>>(hb, gam, bet);
    k_dec_mfma<<<256, 256, 0, stream>>>(hb, WdT, bd, out);
}

// Round 7
// 348.635 us; speedup vs baseline: 1.0028x; 1.0028x over previous
//
#include <hip/hip_runtime.h>
#include <hip/hip_bf16.h>
#include <math.h>

#define B_ 32
#define S_ 128
#define L_ 1024
#define D_ 1024

typedef unsigned short u16;
typedef __attribute__((ext_vector_type(8))) __bf16 bf16x8;
typedef __attribute__((ext_vector_type(4))) float f32x4;

__device__ __forceinline__ float bf2f(u16 u) {
    return __uint_as_float(((unsigned)u) << 16);
}
__device__ __forceinline__ u16 f2bf(float f) {
    unsigned u = __float_as_uint(f);
    u += 0x7FFF + ((u >> 16) & 1);
    return (u16)(u >> 16);
}
__device__ __forceinline__ float gelu_tanh(float x) {
    float x3 = x * x * x;
    float t = tanhf(0.7978845608028654f * (x + 0.044715f * x3));
    return 0.5f * x * (1.0f + t);
}
__device__ __forceinline__ float sigmoidf(float x) {
    return 1.0f / (1.0f + expf(-x));
}
__device__ __forceinline__ void gld16(const void* g, void* l) {
    __builtin_amdgcn_global_load_lds((const __attribute__((address_space(1))) void*)g,
                                     (__attribute__((address_space(3))) void*)l, 16, 0, 0);
}

// ---------------- K0: S4D SSM kernel ---------------------------------------
__global__ __launch_bounds__(256) void k_ssmk(
        const float* __restrict__ log_dt, const float* __restrict__ Alr,
        const float* __restrict__ Aim, const float* __restrict__ Cr,
        const float* __restrict__ Ci, float* __restrict__ Kt) {
    int tid = blockIdx.x * 256 + threadIdx.x;
    int d = tid & (D_ - 1);
    int j = tid >> 10;
    float dt = expf(log_dt[d]);
    float acc = 0.f;
    #pragma unroll
    for (int n = 0; n < 4; ++n) {
        float ar = -expf(Alr[d * 4 + n]);
        float ai = Aim[d * 4 + n];
        float wr = ar * dt, wi = ai * dt;
        float ew = expf(wr);
        float sw, cw; sincosf(wi, &sw, &cw);
        float ur = ew * cw - 1.0f, ui = ew * sw;
        float inv = 1.0f / (ar * ar + ai * ai);
        float bdr = (ur * ar + ui * ai) * inv;
        float bdi = (ui * ar - ur * ai) * inv;
        float cr = Cr[d * 4 + n], ci = Ci[d * 4 + n];
        float cbr = cr * bdr - ci * bdi;
        float cbi = cr * bdi + ci * bdr;
        float ej = expf(wr * (float)j);
        float sj, cj; sincosf(wi * (float)j, &sj, &cj);
        acc += 2.0f * ej * (cbr * cj - cbi * sj);
    }
    Kt[j * D_ + d] = acc;
}

// ---------------- transpose+cast: f32 [R][C] -> bf16 [C][R], batched z -----
__global__ __launch_bounds__(256) void k_tcast(
        const float* __restrict__ src0, u16* __restrict__ dst0, int R, int C) {
    __shared__ float tile[64][65];
    const float* src = src0 + (size_t)blockIdx.z * R * C;
    u16* dst = dst0 + (size_t)blockIdx.z * R * C;
    int c0 = blockIdx.x * 64;
    int r0 = blockIdx.y * 64;
    int t = threadIdx.x;
    #pragma unroll
    for (int p = 0; p < 4; ++p) {
        int fid = p * 256 + t;
        int rr = fid >> 4, cc = (fid & 15) * 4;
        float4 v = *(const float4*)&src[(size_t)(r0 + rr) * C + c0 + cc];
        tile[rr][cc + 0] = v.x; tile[rr][cc + 1] = v.y;
        tile[rr][cc + 2] = v.z; tile[rr][cc + 3] = v.w;
    }
    __syncthreads();
    #pragma unroll
    for (int p = 0; p < 4; ++p) {
        int fid = p * 256 + t;
        int rr = fid >> 4, cc = (fid & 15) * 4;
        ushort4 o;
        o.x = f2bf(tile[cc + 0][rr]);
        o.y = f2bf(tile[cc + 1][rr]);
        o.z = f2bf(tile[cc + 2][rr]);
        o.w = f2bf(tile[cc + 3][rr]);
        *(ushort4*)&dst[(size_t)(c0 + rr) * R + r0 + cc] = o;
    }
}

// ---------------- K1: encoder MFMA ------------------------------------------
__global__ __launch_bounds__(256) void k_enc_mfma(
        const u16* __restrict__ xb, const u16* __restrict__ WeT,
        const float* __restrict__ be, u16* __restrict__ hb) {
    __shared__ u16 As[128 * 128];
    __shared__ u16 Bs[128 * 128];
    int t = threadIdx.x;
    int lane = t & 63, wid = t >> 6;
    int wr = wid & 1, wc = wid >> 1;
    int orig = blockIdx.x;
    int wgid = (orig & 7) * 256 + (orig >> 3);
    int m0 = (wgid >> 3) * 128;
    int e0 = (wgid & 7) * 128;

    #pragma unroll
    for (int c = 0; c < 8; ++c) {
        int ch = wid * 8 + c;
        int r = ch * 4 + (lane >> 4);
        int g = (lane & 15) ^ (r & 15);
        gld16(&xb[(size_t)(m0 + r) * 128 + g * 8], &As[ch * 512]);
        gld16(&WeT[(size_t)(e0 + r) * 128 + g * 8], &Bs[ch * 512]);
    }
    int co4[4];
    #pragma unroll
    for (int kh = 0; kh < 4; ++kh)
        co4[kh] = ((((lane >> 4) + kh * 4) ^ (lane & 15)) * 8);
    int arow[4], brow[4];
    #pragma unroll
    for (int i = 0; i < 4; ++i) arow[i] = (wr * 64 + i * 16 + (lane & 15)) * 128;
    #pragma unroll
    for (int q = 0; q < 4; ++q) brow[q] = (wc * 64 + q * 16 + (lane & 15)) * 128;

    __syncthreads();
    f32x4 acc[4][4] = {};
    #pragma unroll
    for (int kh = 0; kh < 4; ++kh) {
        bf16x8 af[4], bfr[4];
        #pragma unroll
        for (int i = 0; i < 4; ++i) af[i] = *(const bf16x8*)&As[arow[i] + co4[kh]];
        #pragma unroll
        for (int q = 0; q < 4; ++q) bfr[q] = *(const bf16x8*)&Bs[brow[q] + co4[kh]];
        __builtin_amdgcn_s_setprio(1);
        #pragma unroll
        for (int i = 0; i < 4; ++i)
            #pragma unroll
            for (int q = 0; q < 4; ++q)
                acc[i][q] = __builtin_amdgcn_mfma_f32_16x16x32_bf16(af[i], bfr[q], acc[i][q], 0, 0, 0);
        __builtin_amdgcn_s_setprio(0);
    }
    #pragma unroll
    for (int q = 0; q < 4; ++q) {
        int e = e0 + wc * 64 + q * 16 + (lane & 15);
        float bias = be[e];
        #pragma unroll
        for (int i = 0; i < 4; ++i) {
            #pragma unroll
            for (int r = 0; r < 4; ++r) {
                int m = m0 + wr * 64 + i * 16 + (lane >> 4) * 4 + r;
                hb[(size_t)m * 1024 + e] = f2bf(acc[i][q][r] + bias);
            }
        }
    }
}

// ---------------- K2: causal 64-tap conv + D*skip + GELU -------------------
__global__ __launch_bounds__(256) void k_conv(
        const u16* __restrict__ hb, const float* __restrict__ Kt,
        const float* __restrict__ Dv, u16* __restrict__ yg) {
    __shared__ float hs[128][64];
    int b = blockIdx.z;
    int l0 = blockIdx.y * 64;
    int d0 = blockIdx.x * 64;
    int t = threadIdx.x;
    int dl = t & 63, lg = t >> 6;
    #pragma unroll
    for (int p = 0; p < 8; ++p) {
        int fid = p * 256 + t;
        int r = fid >> 4, c4 = fid & 15;
        int l = l0 - 64 + r;
        float4 v = make_float4(0.f, 0.f, 0.f, 0.f);
        if (l >= 0) {
            ushort4 u = *(const ushort4*)&hb[((size_t)b * 1024 + l) * 1024 + d0 + c4 * 4];
            v = make_float4(bf2f(u.x), bf2f(u.y), bf2f(u.z), bf2f(u.w));
        }
        *(float4*)&hs[r][c4 * 4] = v;
    }
    float kr[64];
    #pragma unroll
    for (int j = 0; j < 64; ++j) kr[j] = Kt[j * 1024 + d0 + dl];
    float Dd = Dv[d0 + dl];
    __syncthreads();
    float acc[16] = {};
    int rbase = lg * 16 + 1;
    #pragma unroll
    for (int s = 0; s < 15; ++s) {
        float hv = hs[rbase + s][dl];
        #pragma unroll
        for (int i = 0; i <= 14; ++i)
            if (i <= s) acc[i] = fmaf(kr[i + 63 - s], hv, acc[i]);
    }
    #pragma unroll
    for (int s = 15; s < 64; ++s) {
        float hv = hs[rbase + s][dl];
        #pragma unroll
        for (int i = 0; i < 16; ++i)
            acc[i] = fmaf(kr[i + 63 - s], hv, acc[i]);
    }
    #pragma unroll
    for (int s = 64; s < 79; ++s) {
        float hv = hs[rbase + s][dl];
        #pragma unroll
        for (int i = 1; i < 16; ++i)
            if (i >= s - 63) acc[i] = fmaf(kr[i + 63 - s], hv, acc[i]);
    }
    #pragma unroll
    for (int i = 0; i < 16; ++i) {
        int l = l0 + lg * 16 + i;
        float z = hs[64 + lg * 16 + i][dl];
        float y = acc[i] + Dd * z;
        yg[((size_t)b * 1024 + l) * 1024 + d0 + dl] = f2bf(gelu_tanh(y));
    }
}

// ---------------- K3: GLU GEMM 256x256, half-tile region pipeline ----------
// BM=256, BN=256 (=128 g1/g2 pairs), BK=64, 16 K-tiles, 8 waves (2m x 4n).
// LDS: per operand [2 dbuf][2 half] regions of [128 rows][64 k] = 16 KB; 128 KB.
// A-half h = rows {h*64..h*64+63} of each 128-row wave group (msub interleave).
// B-half h = rows {h*32..} of each 64-row wave group (nsub interleave).
// Phases (msub,nsub): (0,0),(0,1),(1,0),(1,1). Region read windows: A0:P0-P1,
// A1:P2-P3, B0:P0&P2, B1:P1&P3. Stage slots: P0->B1(t+1), P1->A1(t+1),
// P2->A0(t+2), P3->B0(t+2); all stage->read distances 5-6 phases.
// One vmcnt(4) per tile at P0 (certifies tile t, leaves 2 half-tiles in flight).
__global__ __launch_bounds__(512, 2) void k_glu256(
        const u16* __restrict__ yg, const u16* __restrict__ WgT,
        const float* __restrict__ bg, u16* __restrict__ hb) {
    __shared__ u16 S[65536];   // A: [buf*2+h]*8192, B: 32768 + [buf*2+h]*8192
    int t = threadIdx.x;
    int lane = t & 63, wid = t >> 6;
    int wr = wid >> 2, wc = wid & 3;

    int orig = blockIdx.x;
    int wgid = (orig & 7) * 128 + (orig >> 3);   // bijective (1024 % 8 == 0)
    int m0 = (wgid >> 3) * 256;
    int p0g = (wgid & 7) * 128;

    // ---- staging geometry: half-tile region = 16 chunks of 8 rows; wave wid
    // owns chunks {2*wid, 2*wid+1}; lane -> row lane>>3, granule slot lane&7.
    int gofs = (((lane & 7) ^ ((lane >> 3) & 7)) * 8);   // swizzled src granule
    int ch0 = wid * 2, ch1 = ch0 + 1;
    int dst0 = ch0 * 512 + lane * 8;
    int dst1 = ch1 * 512 + lane * 8;
    // A global rows per (half, chunk j): m0 + (ch>>3)*128 + h*64 + (ch&7)*8 + lane>>3
    int gmA[2][2], gmB[2][2];
    #pragma unroll
    for (int h = 0; h < 2; ++h) {
        #pragma unroll
        for (int j = 0; j < 2; ++j) {
            int ch = ch0 + j;
            gmA[h][j] = m0 + (ch >> 3) * 128 + h * 64 + (ch & 7) * 8 + (lane >> 3);
            int r = (ch >> 2) * 64 + h * 32 + (ch & 3) * 8 + (lane >> 3);  // tile n-row
            gmB[h][j] = ((r >> 4) & 1) * 1024 + p0g + (((r >> 5) << 4) | (r & 15));
        }
    }
    // ---- fragment read offsets
    int co[2];
    co[0] = (((lane >> 4) + 0) ^ (lane & 7)) * 8;
    co[1] = (((lane >> 4) + 4) ^ (lane & 7)) * 8;
    int arow[4], brow[2];
    #pragma unroll
    for (int i = 0; i < 4; ++i) arow[i] = (wr * 64 + i * 16 + (lane & 15)) * 64;
    #pragma unroll
    for (int q = 0; q < 2; ++q) brow[q] = (wc * 32 + q * 16 + (lane & 15)) * 64;

#define GLD_A(H, BUF, K0) { u16* d_ = &S[((BUF) * 2 + (H)) * 8192]; \
    gld16(&yg[(size_t)gmA[H][0] * 1024 + (K0) + gofs], d_ + dst0); \
    gld16(&yg[(size_t)gmA[H][1] * 1024 + (K0) + gofs], d_ + dst1); }
#define GLD_B(H, BUF, K0) { u16* d_ = &S[32768 + ((BUF) * 2 + (H)) * 8192]; \
    gld16(&WgT[(size_t)gmB[H][0] * 1024 + (K0) + gofs], d_ + dst0); \
    gld16(&WgT[(size_t)gmB[H][1] * 1024 + (K0) + gofs], d_ + dst1); }

#define PHASE(MS, NS, STAGE_STMT) { \
    const u16* Ar_ = &S[(cbuf * 2 + (MS)) * 8192]; \
    const u16* Br_ = &S[32768 + (cbuf * 2 + (NS)) * 8192]; \
    bf16x8 a_[4][2], b_[2][2]; \
    _Pragma("unroll") for (int q = 0; q < 2; ++q) { \
        b_[q][0] = *(const bf16x8*)&Br_[brow[q] + co[0]]; \
        b_[q][1] = *(const bf16x8*)&Br_[brow[q] + co[1]]; } \
    _Pragma("unroll") for (int i = 0; i < 4; ++i) { \
        a_[i][0] = *(const bf16x8*)&Ar_[arow[i] + co[0]]; \
        a_[i][1] = *(const bf16x8*)&Ar_[arow[i] + co[1]]; } \
    STAGE_STMT; \
    __builtin_amdgcn_s_setprio(1); \
    _Pragma("unroll") for (int i = 0; i < 4; ++i) \
        _Pragma("unroll") for (int q = 0; q < 2; ++q) { \
            acc[(MS) * 4 + i][(NS) * 2 + q] = __builtin_amdgcn_mfma_f32_16x16x32_bf16( \
                a_[i][0], b_[q][0], acc[(MS) * 4 + i][(NS) * 2 + q], 0, 0, 0); \
            acc[(MS) * 4 + i][(NS) * 2 + q] = __builtin_amdgcn_mfma_f32_16x16x32_bf16( \
                a_[i][1], b_[q][1], acc[(MS) * 4 + i][(NS) * 2 + q], 0, 0, 0); } \
    __builtin_amdgcn_s_setprio(0); }

#define BAR() { __builtin_amdgcn_s_barrier(); __builtin_amdgcn_sched_barrier(0); }

    f32x4 acc[8][4] = {};

    // prologue (ledger order): A0(0) B0(0) B1(0) A1(0) A0(1) B0(1)
    GLD_A(0, 0, 0); GLD_B(0, 0, 0); GLD_B(1, 0, 0); GLD_A(1, 0, 0);
    GLD_A(0, 1, 64); GLD_B(0, 1, 64);

    for (int kt = 0; kt < 15; ++kt) {
        int cbuf = kt & 1, nbuf = cbuf ^ 1;
        int k1 = (kt + 1) * 64, k2 = (kt + 2) * 64;
        asm volatile("s_waitcnt vmcnt(4)" ::: "memory");
        BAR();
        PHASE(0, 0, { GLD_B(1, nbuf, k1); });
        BAR();
        PHASE(0, 1, { GLD_A(1, nbuf, k1); });
        BAR();
        PHASE(1, 0, { if (kt < 14) GLD_A(0, cbuf, k2); });
        BAR();
        PHASE(1, 1, { if (kt < 14) GLD_B(0, cbuf, k2); });
    }
    // peel kt = 15 (buf 1, no staging)
    {
        int cbuf = 1;
        asm volatile("s_waitcnt vmcnt(0)" ::: "memory");
        BAR();
        PHASE(0, 0, {});
        PHASE(0, 1, {});
        PHASE(1, 0, {});
        PHASE(1, 1, {});
    }
#undef GLD_A
#undef GLD_B
#undef PHASE
#undef BAR

    // epilogue: GLU activation + residual in-place
    #pragma unroll
    for (int i = 0; i < 8; ++i) {
        #pragma unroll
        for (int pb = 0; pb < 2; ++pb) {
            int col = p0g + (wc * 2 + pb) * 16 + (lane & 15);
            float b1v = bg[col];
            float b2v = bg[1024 + col];
            #pragma unroll
            for (int r = 0; r < 4; ++r) {
                int m = m0 + wr * 128 + i * 16 + (lane >> 4) * 4 + r;
                size_t idx = (size_t)m * 1024 + col;
                float g1 = acc[i][pb * 2][r] + b1v;
                float g2 = acc[i][pb * 2 + 1][r] + b2v;
                hb[idx] = f2bf(bf2f(hb[idx]) + g1 * sigmoidf(g2));
            }
        }
    }
}

// ---------------- K4: LayerNorm in-place on hb ------------------------------
__global__ __launch_bounds__(256) void k_ln(
        u16* __restrict__ hb, const float* __restrict__ gamma,
        const float* __restrict__ beta) {
    int row = blockIdx.x;
    int t = threadIdx.x;
    size_t base = (size_t)row * 1024;
    ushort4 u = *(const ushort4*)&hb[base + t * 4];
    float v0 = bf2f(u.x), v1 = bf2f(u.y), v2 = bf2f(u.z), v3 = bf2f(u.w);
    float s = v0 + v1 + v2 + v3;
    float s2 = v0 * v0 + v1 * v1 + v2 * v2 + v3 * v3;
    #pragma unroll
    for (int off = 32; off > 0; off >>= 1) {
        s += __shfl_down(s, off);
        s2 += __shfl_down(s2, off);
    }
    __shared__ float rs[4], rs2[4];
    int wid = t >> 6, lane = t & 63;
    if (lane == 0) { rs[wid] = s; rs2[wid] = s2; }
    __syncthreads();
    float ts = rs[0] + rs[1] + rs[2] + rs[3];
    float ts2 = rs2[0] + rs2[1] + rs2[2] + rs2[3];
    float mean = ts * (1.0f / 1024.0f);
    float var = ts2 * (1.0f / 1024.0f) - mean * mean;
    float rstd = rsqrtf(var + 1e-5f);
    float4 gm = *(const float4*)&gamma[t * 4];
    float4 bt = *(const float4*)&beta[t * 4];
    ushort4 o;
    o.x = f2bf((v0 - mean) * rstd * gm.x + bt.x);
    o.y = f2bf((v1 - mean) * rstd * gm.y + bt.y);
    o.z = f2bf((v2 - mean) * rstd * gm.z + bt.z);
    o.w = f2bf((v3 - mean) * rstd * gm.w + bt.w);
    *(ushort4*)&hb[base + t * 4] = o;
}

// ---------------- K5: decoder GEMM (dbuf + swizzle) + transpose store ------
__global__ __launch_bounds__(256) void k_dec_mfma(
        const u16* __restrict__ hb, const u16* __restrict__ WdT,
        const float* __restrict__ bd, float* __restrict__ out) {
    __shared__ __align__(16) char smem[65536];
    u16* As = (u16*)smem;
    u16* Bs = (u16*)(smem + 32768);
    float* Ts = (float*)smem;
    int t = threadIdx.x;
    int lane = t & 63, wid = t >> 6;
    int wr = wid & 1, wc = wid >> 1;
    int m0 = blockIdx.x * 128;
    int bb = m0 >> 10, l0 = m0 & 1023;

    int gsrc = (((lane & 7) ^ (lane >> 3)) * 8);
    int rr4[4];
    #pragma unroll
    for (int c = 0; c < 4; ++c) rr4[c] = (wid * 4 + c) * 8 + (lane >> 3);
    int co[2];
    co[0] = (((lane >> 4) + 0) ^ (lane & 7)) * 8;
    co[1] = (((lane >> 4) + 4) ^ (lane & 7)) * 8;
    int arow[4], brow[4];
    #pragma unroll
    for (int i = 0; i < 4; ++i) arow[i] = (wr * 64 + i * 16 + (lane & 15)) * 64;
    #pragma unroll
    for (int q = 0; q < 4; ++q) brow[q] = (wc * 64 + q * 16 + (lane & 15)) * 64;

    f32x4 acc[4][4] = {};
    #pragma unroll
    for (int c = 0; c < 4; ++c) {
        int ch = wid * 4 + c;
        gld16(&hb[(size_t)(m0 + rr4[c]) * 1024 + gsrc], &As[0 * 8192 + ch * 512]);
        gld16(&WdT[(size_t)rr4[c] * 1024 + gsrc], &Bs[0 * 8192 + ch * 512]);
    }
    __syncthreads();
    int cur = 0;
    for (int kt = 0; kt < 16; ++kt) {
        if (kt < 15) {
            int k0 = (kt + 1) * 64;
            #pragma unroll
            for (int c = 0; c < 4; ++c) {
                int ch = wid * 4 + c;
                gld16(&hb[(size_t)(m0 + rr4[c]) * 1024 + k0 + gsrc], &As[(cur ^ 1) * 8192 + ch * 512]);
                gld16(&WdT[(size_t)rr4[c] * 1024 + k0 + gsrc], &Bs[(cur ^ 1) * 8192 + ch * 512]);
            }
        }
        #pragma unroll
        for (int kh = 0; kh < 2; ++kh) {
            bf16x8 af[4], bfr[4];
            #pragma unroll
            for (int i = 0; i < 4; ++i) af[i] = *(const bf16x8*)&As[cur * 8192 + arow[i] + co[kh]];
            #pragma unroll
            for (int q = 0; q < 4; ++q) bfr[q] = *(const bf16x8*)&Bs[cur * 8192 + brow[q] + co[kh]];
            __builtin_amdgcn_s_setprio(1);
            #pragma unroll
            for (int i = 0; i < 4; ++i)
                #pragma unroll
                for (int q = 0; q < 4; ++q)
                    acc[i][q] = __builtin_amdgcn_mfma_f32_16x16x32_bf16(af[i], bfr[q], acc[i][q], 0, 0, 0);
            __builtin_amdgcn_s_setprio(0);
        }
        __syncthreads();
        cur ^= 1;
    }
    __syncthreads();
    #pragma unroll
    for (int ro = 0; ro < 2; ++ro) {
        if (wc == ro) {
            #pragma unroll
            for (int i = 0; i < 4; ++i)
                #pragma unroll
                for (int q = 0; q < 4; ++q) {
                    int sl = q * 16 + (lane & 15);
                    float bias = bd[ro * 64 + sl];
                    #pragma unroll
                    for (int r = 0; r < 4; ++r) {
                        int ml = wr * 64 + i * 16 + (lane >> 4) * 4 + r;
                        Ts[sl * 132 + ml] = acc[i][q][r] + bias;
                    }
                }
        }
        __syncthreads();
        #pragma unroll
        for (int p = 0; p < 8; ++p) {
            int fid = p * 256 + t;
            int sl = fid >> 5, c = (fid & 31) * 4;
            float4 v = *(const float4*)&Ts[sl * 132 + c];
            *(float4*)&out[(size_t)bb * 131072 + (size_t)(ro * 64 + sl) * 1024 + l0 + c] = v;
        }
        __syncthreads();
    }
}

extern "C" void kernel_launch(void* const* d_in, const int* in_sizes, int n_in,
                              void* d_out, int out_size, void* d_ws, size_t ws_size,
                              hipStream_t stream) {
    (void)in_sizes; (void)n_in; (void)out_size; (void)ws_size;
    const float* x   = (const float*)d_in[0];
    const float* We  = (const float*)d_in[1];
    const float* be  = (const float*)d_in[2];
    const float* ldt = (const float*)d_in[3];
    const float* Alr = (const float*)d_in[4];
    const float* Aim = (const float*)d_in[5];
    const float* Cr  = (const float*)d_in[6];
    const float* Ci  = (const float*)d_in[7];
    const float* Dv  = (const float*)d_in[8];
    const float* Wg  = (const float*)d_in[9];
    const float* bg  = (const float*)d_in[10];
    const float* gam = (const float*)d_in[11];
    const float* bet = (const float*)d_in[12];
    const float* Wd  = (const float*)d_in[13];
    const float* bd  = (const float*)d_in[14];
    float* out = (float*)d_out;

    u16* hb = (u16*)d_ws;                       // 67 MB
    u16* yg = hb + 33554432ull;                 // 67 MB
    float* Kt = (float*)(yg + 33554432ull);     // 256 KB
    u16* WgT = (u16*)(Kt + 65536);              // 4 MB
    u16* WdT = WgT + 2097152ull;                // 256 KB
    u16* WeT = WdT + 131072ull;                 // 256 KB
    u16* xb  = yg;                              // alias: xb dead before conv writes yg

    k_tcast<<<dim3(32, 16, 1), 256, 0, stream>>>(Wg, WgT, 1024, 2048);
    k_tcast<<<dim3(2, 16, 1), 256, 0, stream>>>(Wd, WdT, 1024, 128);
    k_tcast<<<dim3(16, 2, 1), 256, 0, stream>>>(We, WeT, 128, 1024);
    k_tcast<<<dim3(16, 2, 32), 256, 0, stream>>>(x, xb, 128, 1024);
    k_ssmk<<<256, 256, 0, stream>>>(ldt, Alr, Aim, Cr, Ci, Kt);
    k_enc_mfma<<<2048, 256, 0, stream>>>(xb, WeT, be, hb);
    k_conv<<<dim3(16, 16, 32), 256, 0, stream>>>(hb, Kt, Dv, yg);
    k_glu256<<<1024, 512, 0, stream>>>(yg, WgT, bg, hb);
    k_ln<<<32768, 256, 0, stream>>>(hb, gam, bet);
    k_dec_mfma<<<256, 256, 0, stream>>>(hb, WdT, bd, out);
}

// Round 8
// 342.999 us; speedup vs baseline: 1.0192x; 1.0164x over previous
//
#include <hip/hip_runtime.h>
#include <hip/hip_bf16.h>
#include <math.h>

#define B_ 32
#define S_ 128
#define L_ 1024
#define D_ 1024

typedef unsigned short u16;
typedef __attribute__((ext_vector_type(8))) __bf16 bf16x8;
typedef __attribute__((ext_vector_type(4))) float f32x4;

__device__ __forceinline__ float bf2f(u16 u) {
    return __uint_as_float(((unsigned)u) << 16);
}
__device__ __forceinline__ u16 f2bf(float f) {
    unsigned u = __float_as_uint(f);
    u += 0x7FFF + ((u >> 16) & 1);
    return (u16)(u >> 16);
}
__device__ __forceinline__ float gelu_tanh(float x) {
    float x3 = x * x * x;
    float t = tanhf(0.7978845608028654f * (x + 0.044715f * x3));
    return 0.5f * x * (1.0f + t);
}
__device__ __forceinline__ float sigmoidf(float x) {
    return 1.0f / (1.0f + expf(-x));
}
__device__ __forceinline__ void gld16(const void* g, void* l) {
    __builtin_amdgcn_global_load_lds((const __attribute__((address_space(1))) void*)g,
                                     (__attribute__((address_space(3))) void*)l, 16, 0, 0);
}

// ---------------- K0: S4D SSM kernel ---------------------------------------
__global__ __launch_bounds__(256) void k_ssmk(
        const float* __restrict__ log_dt, const float* __restrict__ Alr,
        const float* __restrict__ Aim, const float* __restrict__ Cr,
        const float* __restrict__ Ci, float* __restrict__ Kt) {
    int tid = blockIdx.x * 256 + threadIdx.x;
    int d = tid & (D_ - 1);
    int j = tid >> 10;
    float dt = expf(log_dt[d]);
    float acc = 0.f;
    #pragma unroll
    for (int n = 0; n < 4; ++n) {
        float ar = -expf(Alr[d * 4 + n]);
        float ai = Aim[d * 4 + n];
        float wr = ar * dt, wi = ai * dt;
        float ew = expf(wr);
        float sw, cw; sincosf(wi, &sw, &cw);
        float ur = ew * cw - 1.0f, ui = ew * sw;
        float inv = 1.0f / (ar * ar + ai * ai);
        float bdr = (ur * ar + ui * ai) * inv;
        float bdi = (ui * ar - ur * ai) * inv;
        float cr = Cr[d * 4 + n], ci = Ci[d * 4 + n];
        float cbr = cr * bdr - ci * bdi;
        float cbi = cr * bdi + ci * bdr;
        float ej = expf(wr * (float)j);
        float sj, cj; sincosf(wi * (float)j, &sj, &cj);
        acc += 2.0f * ej * (cbr * cj - cbi * sj);
    }
    Kt[j * D_ + d] = acc;
}

// ---------------- transpose+cast: f32 [R][C] -> bf16 [C][R], batched z -----
__global__ __launch_bounds__(256) void k_tcast(
        const float* __restrict__ src0, u16* __restrict__ dst0, int R, int C) {
    __shared__ float tile[64][65];
    const float* src = src0 + (size_t)blockIdx.z * R * C;
    u16* dst = dst0 + (size_t)blockIdx.z * R * C;
    int c0 = blockIdx.x * 64;
    int r0 = blockIdx.y * 64;
    int t = threadIdx.x;
    #pragma unroll
    for (int p = 0; p < 4; ++p) {
        int fid = p * 256 + t;
        int rr = fid >> 4, cc = (fid & 15) * 4;
        float4 v = *(const float4*)&src[(size_t)(r0 + rr) * C + c0 + cc];
        tile[rr][cc + 0] = v.x; tile[rr][cc + 1] = v.y;
        tile[rr][cc + 2] = v.z; tile[rr][cc + 3] = v.w;
    }
    __syncthreads();
    #pragma unroll
    for (int p = 0; p < 4; ++p) {
        int fid = p * 256 + t;
        int rr = fid >> 4, cc = (fid & 15) * 4;
        ushort4 o;
        o.x = f2bf(tile[cc + 0][rr]);
        o.y = f2bf(tile[cc + 1][rr]);
        o.z = f2bf(tile[cc + 2][rr]);
        o.w = f2bf(tile[cc + 3][rr]);
        *(ushort4*)&dst[(size_t)(c0 + rr) * R + r0 + cc] = o;
    }
}

// ---------------- K1: encoder MFMA ------------------------------------------
__global__ __launch_bounds__(256) void k_enc_mfma(
        const u16* __restrict__ xb, const u16* __restrict__ WeT,
        const float* __restrict__ be, u16* __restrict__ hb) {
    __shared__ u16 As[128 * 128];
    __shared__ u16 Bs[128 * 128];
    int t = threadIdx.x;
    int lane = t & 63, wid = t >> 6;
    int wr = wid & 1, wc = wid >> 1;
    int orig = blockIdx.x;
    int wgid = (orig & 7) * 256 + (orig >> 3);
    int m0 = (wgid >> 3) * 128;
    int e0 = (wgid & 7) * 128;

    #pragma unroll
    for (int c = 0; c < 8; ++c) {
        int ch = wid * 8 + c;
        int r = ch * 4 + (lane >> 4);
        int g = (lane & 15) ^ (r & 15);
        gld16(&xb[(size_t)(m0 + r) * 128 + g * 8], &As[ch * 512]);
        gld16(&WeT[(size_t)(e0 + r) * 128 + g * 8], &Bs[ch * 512]);
    }
    int co4[4];
    #pragma unroll
    for (int kh = 0; kh < 4; ++kh)
        co4[kh] = ((((lane >> 4) + kh * 4) ^ (lane & 15)) * 8);
    int arow[4], brow[4];
    #pragma unroll
    for (int i = 0; i < 4; ++i) arow[i] = (wr * 64 + i * 16 + (lane & 15)) * 128;
    #pragma unroll
    for (int q = 0; q < 4; ++q) brow[q] = (wc * 64 + q * 16 + (lane & 15)) * 128;

    __syncthreads();
    f32x4 acc[4][4] = {};
    #pragma unroll
    for (int kh = 0; kh < 4; ++kh) {
        bf16x8 af[4], bfr[4];
        #pragma unroll
        for (int i = 0; i < 4; ++i) af[i] = *(const bf16x8*)&As[arow[i] + co4[kh]];
        #pragma unroll
        for (int q = 0; q < 4; ++q) bfr[q] = *(const bf16x8*)&Bs[brow[q] + co4[kh]];
        __builtin_amdgcn_s_setprio(1);
        #pragma unroll
        for (int i = 0; i < 4; ++i)
            #pragma unroll
            for (int q = 0; q < 4; ++q)
                acc[i][q] = __builtin_amdgcn_mfma_f32_16x16x32_bf16(af[i], bfr[q], acc[i][q], 0, 0, 0);
        __builtin_amdgcn_s_setprio(0);
    }
    #pragma unroll
    for (int q = 0; q < 4; ++q) {
        int e = e0 + wc * 64 + q * 16 + (lane & 15);
        float bias = be[e];
        #pragma unroll
        for (int i = 0; i < 4; ++i) {
            #pragma unroll
            for (int r = 0; r < 4; ++r) {
                int m = m0 + wr * 64 + i * 16 + (lane >> 4) * 4 + r;
                hb[(size_t)m * 1024 + e] = f2bf(acc[i][q][r] + bias);
            }
        }
    }
}

// ---------------- K2: causal 64-tap conv + D*skip + GELU -------------------
__global__ __launch_bounds__(256) void k_conv(
        const u16* __restrict__ hb, const float* __restrict__ Kt,
        const float* __restrict__ Dv, u16* __restrict__ yg) {
    __shared__ float hs[128][64];
    int b = blockIdx.z;
    int l0 = blockIdx.y * 64;
    int d0 = blockIdx.x * 64;
    int t = threadIdx.x;
    int dl = t & 63, lg = t >> 6;
    #pragma unroll
    for (int p = 0; p < 8; ++p) {
        int fid = p * 256 + t;
        int r = fid >> 4, c4 = fid & 15;
        int l = l0 - 64 + r;
        float4 v = make_float4(0.f, 0.f, 0.f, 0.f);
        if (l >= 0) {
            ushort4 u = *(const ushort4*)&hb[((size_t)b * 1024 + l) * 1024 + d0 + c4 * 4];
            v = make_float4(bf2f(u.x), bf2f(u.y), bf2f(u.z), bf2f(u.w));
        }
        *(float4*)&hs[r][c4 * 4] = v;
    }
    float kr[64];
    #pragma unroll
    for (int j = 0; j < 64; ++j) kr[j] = Kt[j * 1024 + d0 + dl];
    float Dd = Dv[d0 + dl];
    __syncthreads();
    float acc[16] = {};
    int rbase = lg * 16 + 1;
    #pragma unroll
    for (int s = 0; s < 15; ++s) {
        float hv = hs[rbase + s][dl];
        #pragma unroll
        for (int i = 0; i <= 14; ++i)
            if (i <= s) acc[i] = fmaf(kr[i + 63 - s], hv, acc[i]);
    }
    #pragma unroll
    for (int s = 15; s < 64; ++s) {
        float hv = hs[rbase + s][dl];
        #pragma unroll
        for (int i = 0; i < 16; ++i)
            acc[i] = fmaf(kr[i + 63 - s], hv, acc[i]);
    }
    #pragma unroll
    for (int s = 64; s < 79; ++s) {
        float hv = hs[rbase + s][dl];
        #pragma unroll
        for (int i = 1; i < 16; ++i)
            if (i >= s - 63) acc[i] = fmaf(kr[i + 63 - s], hv, acc[i]);
    }
    #pragma unroll
    for (int i = 0; i < 16; ++i) {
        int l = l0 + lg * 16 + i;
        float z = hs[64 + lg * 16 + i][dl];
        float y = acc[i] + Dd * z;
        yg[((size_t)b * 1024 + l) * 1024 + d0 + dl] = f2bf(gelu_tanh(y));
    }
}

// ---------------- K3: GLU GEMM 256x256, read-once fragment pipeline --------
// Same regions/stage-slots/vmcnt ledger as r7; change: each fragment is
// ds_read ONCE per K-tile and held in registers (24 b128/wave/tile vs 48),
// halving LDS read traffic (the measured bottleneck).
__global__ __launch_bounds__(512, 2) void k_glu256(
        const u16* __restrict__ yg, const u16* __restrict__ WgT,
        const float* __restrict__ bg, u16* __restrict__ hb) {
    __shared__ u16 S[65536];   // A: [buf*2+h]*8192, B: 32768 + [buf*2+h]*8192
    int t = threadIdx.x;
    int lane = t & 63, wid = t >> 6;
    int wr = wid >> 2, wc = wid & 3;

    int orig = blockIdx.x;
    int wgid = (orig & 7) * 128 + (orig >> 3);   // bijective (1024 % 8 == 0)
    int m0 = (wgid >> 3) * 256;
    int p0g = (wgid & 7) * 128;

    // staging geometry (unchanged from r7)
    int gofs = (((lane & 7) ^ ((lane >> 3) & 7)) * 8);
    int ch0 = wid * 2, ch1 = ch0 + 1;
    int dst0 = ch0 * 512 + lane * 8;
    int dst1 = ch1 * 512 + lane * 8;
    int gmA[2][2], gmB[2][2];
    #pragma unroll
    for (int h = 0; h < 2; ++h) {
        #pragma unroll
        for (int j = 0; j < 2; ++j) {
            int ch = ch0 + j;
            gmA[h][j] = m0 + (ch >> 3) * 128 + h * 64 + (ch & 7) * 8 + (lane >> 3);
            int r = (ch >> 2) * 64 + h * 32 + (ch & 3) * 8 + (lane >> 3);
            gmB[h][j] = ((r >> 4) & 1) * 1024 + p0g + (((r >> 5) << 4) | (r & 15));
        }
    }
    // fragment read offsets (unchanged)
    int co[2];
    co[0] = (((lane >> 4) + 0) ^ (lane & 7)) * 8;
    co[1] = (((lane >> 4) + 4) ^ (lane & 7)) * 8;
    int arow[4], brow[2];
    #pragma unroll
    for (int i = 0; i < 4; ++i) arow[i] = (wr * 64 + i * 16 + (lane & 15)) * 64;
    #pragma unroll
    for (int q = 0; q < 2; ++q) brow[q] = (wc * 32 + q * 16 + (lane & 15)) * 64;

#define GLD_A(H, BUF, K0) { u16* d_ = &S[((BUF) * 2 + (H)) * 8192]; \
    gld16(&yg[(size_t)gmA[H][0] * 1024 + (K0) + gofs], d_ + dst0); \
    gld16(&yg[(size_t)gmA[H][1] * 1024 + (K0) + gofs], d_ + dst1); }
#define GLD_B(H, BUF, K0) { u16* d_ = &S[32768 + ((BUF) * 2 + (H)) * 8192]; \
    gld16(&WgT[(size_t)gmB[H][0] * 1024 + (K0) + gofs], d_ + dst0); \
    gld16(&WgT[(size_t)gmB[H][1] * 1024 + (K0) + gofs], d_ + dst1); }

#define RD_AH(MS) { const u16* Ar_ = &S[(cbuf * 2 + (MS)) * 8192]; \
    _Pragma("unroll") for (int i = 0; i < 4; ++i) { \
        a_[i][0] = *(const bf16x8*)&Ar_[arow[i] + co[0]]; \
        a_[i][1] = *(const bf16x8*)&Ar_[arow[i] + co[1]]; } }
#define RD_BH(NS, BB) { const u16* Br_ = &S[32768 + (cbuf * 2 + (NS)) * 8192]; \
    _Pragma("unroll") for (int q = 0; q < 2; ++q) { \
        BB[q][0] = *(const bf16x8*)&Br_[brow[q] + co[0]]; \
        BB[q][1] = *(const bf16x8*)&Br_[brow[q] + co[1]]; } }
#define MFMA16(MS, NS, BB) { __builtin_amdgcn_s_setprio(1); \
    _Pragma("unroll") for (int i = 0; i < 4; ++i) \
        _Pragma("unroll") for (int q = 0; q < 2; ++q) { \
            acc[(MS) * 4 + i][(NS) * 2 + q] = __builtin_amdgcn_mfma_f32_16x16x32_bf16( \
                a_[i][0], BB[q][0], acc[(MS) * 4 + i][(NS) * 2 + q], 0, 0, 0); \
            acc[(MS) * 4 + i][(NS) * 2 + q] = __builtin_amdgcn_mfma_f32_16x16x32_bf16( \
                a_[i][1], BB[q][1], acc[(MS) * 4 + i][(NS) * 2 + q], 0, 0, 0); } \
    __builtin_amdgcn_s_setprio(0); }
#define BAR() { __builtin_amdgcn_s_barrier(); __builtin_amdgcn_sched_barrier(0); }

    f32x4 acc[8][4] = {};
    bf16x8 a_[4][2], b0_[2][2], b1_[2][2];

    // prologue (ledger order): A0(0) B0(0) B1(0) A1(0) A0(1) B0(1)
    GLD_A(0, 0, 0); GLD_B(0, 0, 0); GLD_B(1, 0, 0); GLD_A(1, 0, 0);
    GLD_A(0, 1, 64); GLD_B(0, 1, 64);

    for (int kt = 0; kt < 15; ++kt) {
        int cbuf = kt & 1, nbuf = cbuf ^ 1;
        int k1 = (kt + 1) * 64, k2 = (kt + 2) * 64;
        asm volatile("s_waitcnt vmcnt(4)" ::: "memory");
        BAR();
        // P0: read all B frags + A half0 (once per tile), cluster A0xB0
        RD_BH(0, b0_); RD_BH(1, b1_); RD_AH(0);
        GLD_B(1, nbuf, k1);
        MFMA16(0, 0, b0_);
        BAR();
        // P1: cluster A0xB1
        GLD_A(1, nbuf, k1);
        MFMA16(0, 1, b1_);
        BAR();
        // P2: read A half1, cluster A1xB0
        RD_AH(1);
        if (kt < 14) GLD_A(0, cbuf, k2);
        MFMA16(1, 0, b0_);
        BAR();
        // P3: cluster A1xB1
        if (kt < 14) GLD_B(0, cbuf, k2);
        MFMA16(1, 1, b1_);
    }
    // peel kt = 15 (buf 1, no staging)
    {
        int cbuf = 1;
        asm volatile("s_waitcnt vmcnt(0)" ::: "memory");
        BAR();
        RD_BH(0, b0_); RD_BH(1, b1_); RD_AH(0);
        MFMA16(0, 0, b0_);
        MFMA16(0, 1, b1_);
        RD_AH(1);
        MFMA16(1, 0, b0_);
        MFMA16(1, 1, b1_);
    }
#undef GLD_A
#undef GLD_B
#undef RD_AH
#undef RD_BH
#undef MFMA16
#undef BAR

    // epilogue: GLU activation + residual in-place
    #pragma unroll
    for (int i = 0; i < 8; ++i) {
        #pragma unroll
        for (int pb = 0; pb < 2; ++pb) {
            int col = p0g + (wc * 2 + pb) * 16 + (lane & 15);
            float b1v = bg[col];
            float b2v = bg[1024 + col];
            #pragma unroll
            for (int r = 0; r < 4; ++r) {
                int m = m0 + wr * 128 + i * 16 + (lane >> 4) * 4 + r;
                size_t idx = (size_t)m * 1024 + col;
                float g1 = acc[i][pb * 2][r] + b1v;
                float g2 = acc[i][pb * 2 + 1][r] + b2v;
                hb[idx] = f2bf(bf2f(hb[idx]) + g1 * sigmoidf(g2));
            }
        }
    }
}

// ---------------- K4: LayerNorm in-place on hb ------------------------------
__global__ __launch_bounds__(256) void k_ln(
        u16* __restrict__ hb, const float* __restrict__ gamma,
        const float* __restrict__ beta) {
    int row = blockIdx.x;
    int t = threadIdx.x;
    size_t base = (size_t)row * 1024;
    ushort4 u = *(const ushort4*)&hb[base + t * 4];
    float v0 = bf2f(u.x), v1 = bf2f(u.y), v2 = bf2f(u.z), v3 = bf2f(u.w);
    float s = v0 + v1 + v2 + v3;
    float s2 = v0 * v0 + v1 * v1 + v2 * v2 + v3 * v3;
    #pragma unroll
    for (int off = 32; off > 0; off >>= 1) {
        s += __shfl_down(s, off);
        s2 += __shfl_down(s2, off);
    }
    __shared__ float rs[4], rs2[4];
    int wid = t >> 6, lane = t & 63;
    if (lane == 0) { rs[wid] = s; rs2[wid] = s2; }
    __syncthreads();
    float ts = rs[0] + rs[1] + rs[2] + rs[3];
    float ts2 = rs2[0] + rs2[1] + rs2[2] + rs2[3];
    float mean = ts * (1.0f / 1024.0f);
    float var = ts2 * (1.0f / 1024.0f) - mean * mean;
    float rstd = rsqrtf(var + 1e-5f);
    float4 gm = *(const float4*)&gamma[t * 4];
    float4 bt = *(const float4*)&beta[t * 4];
    ushort4 o;
    o.x = f2bf((v0 - mean) * rstd * gm.x + bt.x);
    o.y = f2bf((v1 - mean) * rstd * gm.y + bt.y);
    o.z = f2bf((v2 - mean) * rstd * gm.z + bt.z);
    o.w = f2bf((v3 - mean) * rstd * gm.w + bt.w);
    *(ushort4*)&hb[base + t * 4] = o;
}

// ---------------- K5: decoder GEMM (dbuf + swizzle) + transpose store ------
__global__ __launch_bounds__(256) void k_dec_mfma(
        const u16* __restrict__ hb, const u16* __restrict__ WdT,
        const float* __restrict__ bd, float* __restrict__ out) {
    __shared__ __align__(16) char smem[65536];
    u16* As = (u16*)smem;
    u16* Bs = (u16*)(smem + 32768);
    float* Ts = (float*)smem;
    int t = threadIdx.x;
    int lane = t & 63, wid = t >> 6;
    int wr = wid & 1, wc = wid >> 1;
    int m0 = blockIdx.x * 128;
    int bb = m0 >> 10, l0 = m0 & 1023;

    int gsrc = (((lane & 7) ^ (lane >> 3)) * 8);
    int rr4[4];
    #pragma unroll
    for (int c = 0; c < 4; ++c) rr4[c] = (wid * 4 + c) * 8 + (lane >> 3);
    int co[2];
    co[0] = (((lane >> 4) + 0) ^ (lane & 7)) * 8;
    co[1] = (((lane >> 4) + 4) ^ (lane & 7)) * 8;
    int arow[4], brow[4];
    #pragma unroll
    for (int i = 0; i < 4; ++i) arow[i] = (wr * 64 + i * 16 + (lane & 15)) * 64;
    #pragma unroll
    for (int q = 0; q < 4; ++q) brow[q] = (wc * 64 + q * 16 + (lane & 15)) * 64;

    f32x4 acc[4][4] = {};
    #pragma unroll
    for (int c = 0; c < 4; ++c) {
        int ch = wid * 4 + c;
        gld16(&hb[(size_t)(m0 + rr4[c]) * 1024 + gsrc], &As[0 * 8192 + ch * 512]);
        gld16(&WdT[(size_t)rr4[c] * 1024 + gsrc], &Bs[0 * 8192 + ch * 512]);
    }
    __syncthreads();
    int cur = 0;
    for (int kt = 0; kt < 16; ++kt) {
        if (kt < 15) {
            int k0 = (kt + 1) * 64;
            #pragma unroll
            for (int c = 0; c < 4; ++c) {
                int ch = wid * 4 + c;
                gld16(&hb[(size_t)(m0 + rr4[c]) * 1024 + k0 + gsrc], &As[(cur ^ 1) * 8192 + ch * 512]);
                gld16(&WdT[(size_t)rr4[c] * 1024 + k0 + gsrc], &Bs[(cur ^ 1) * 8192 + ch * 512]);
            }
        }
        #pragma unroll
        for (int kh = 0; kh < 2; ++kh) {
            bf16x8 af[4], bfr[4];
            #pragma unroll
            for (int i = 0; i < 4; ++i) af[i] = *(const bf16x8*)&As[cur * 8192 + arow[i] + co[kh]];
            #pragma unroll
            for (int q = 0; q < 4; ++q) bfr[q] = *(const bf16x8*)&Bs[cur * 8192 + brow[q] + co[kh]];
            __builtin_amdgcn_s_setprio(1);
            #pragma unroll
            for (int i = 0; i < 4; ++i)
                #pragma unroll
                for (int q = 0; q < 4; ++q)
                    acc[i][q] = __builtin_amdgcn_mfma_f32_16x16x32_bf16(af[i], bfr[q], acc[i][q], 0, 0, 0);
            __builtin_amdgcn_s_setprio(0);
        }
        __syncthreads();
        cur ^= 1;
    }
    __syncthreads();
    #pragma unroll
    for (int ro = 0; ro < 2; ++ro) {
        if (wc == ro) {
            #pragma unroll
            for (int i = 0; i < 4; ++i)
                #pragma unroll
                for (int q = 0; q < 4; ++q) {
                    int sl = q * 16 + (lane & 15);
                    float bias = bd[ro * 64 + sl];
                    #pragma unroll
                    for (int r = 0; r < 4; ++r) {
                        int ml = wr * 64 + i * 16 + (lane >> 4) * 4 + r;
                        Ts[sl * 132 + ml] = acc[i][q][r] + bias;
                    }
                }
        }
        __syncthreads();
        #pragma unroll
        for (int p = 0; p < 8; ++p) {
            int fid = p * 256 + t;
            int sl = fid >> 5, c = (fid & 31) * 4;
            float4 v = *(const float4*)&Ts[sl * 132 + c];
            *(float4*)&out[(size_t)bb * 131072 + (size_t)(ro * 64 + sl) * 1024 + l0 + c] = v;
        }
        __syncthreads();
    }
}

extern "C" void kernel_launch(void* const* d_in, const int* in_sizes, int n_in,
                              void* d_out, int out_size, void* d_ws, size_t ws_size,
                              hipStream_t stream) {
    (void)in_sizes; (void)n_in; (void)out_size; (void)ws_size;
    const float* x   = (const float*)d_in[0];
    const float* We  = (const float*)d_in[1];
    const float* be  = (const float*)d_in[2];
    const float* ldt = (const float*)d_in[3];
    const float* Alr = (const float*)d_in[4];
    const float* Aim = (const float*)d_in[5];
    const float* Cr  = (const float*)d_in[6];
    const float* Ci  = (const float*)d_in[7];
    const float* Dv  = (const float*)d_in[8];
    const float* Wg  = (const float*)d_in[9];
    const float* bg  = (const float*)d_in[10];
    const float* gam = (const float*)d_in[11];
    const float* bet = (const float*)d_in[12];
    const float* Wd  = (const float*)d_in[13];
    const float* bd  = (const float*)d_in[14];
    float* out = (float*)d_out;

    u16* hb = (u16*)d_ws;                       // 67 MB
    u16* yg = hb + 33554432ull;                 // 67 MB
    float* Kt = (float*)(yg + 33554432ull);     // 256 KB
    u16* WgT = (u16*)(Kt + 65536);              // 4 MB
    u16* WdT = WgT + 2097152ull;                // 256 KB
    u16* WeT = WdT + 131072ull;                 // 256 KB
    u16* xb  = yg;                              // alias: xb dead before conv writes yg

    k_tcast<<<dim3(32, 16, 1), 256, 0, stream>>>(Wg, WgT, 1024, 2048);
    k_tcast<<<dim3(2, 16, 1), 256, 0, stream>>>(Wd, WdT, 1024, 128);
    k_tcast<<<dim3(16, 2, 1), 256, 0, stream>>>(We, WeT, 128, 1024);
    k_tcast<<<dim3(16, 2, 32), 256, 0, stream>>>(x, xb, 128, 1024);
    k_ssmk<<<256, 256, 0, stream>>>(ldt, Alr, Aim, Cr, Ci, Kt);
    k_enc_mfma<<<2048, 256, 0, stream>>>(xb, WeT, be, hb);
    k_conv<<<dim3(16, 16, 32), 256, 0, stream>>>(hb, Kt, Dv, yg);
    k_glu256<<<1024, 512, 0, stream>>>(yg, WgT, bg, hb);
    k_ln<<<32768, 256, 0, stream>>>(hb, gam, bet);
    k_dec_mfma<<<256, 256, 0, stream>>>(hb, WdT, bd, out);
}

// Round 9
// 336.231 us; speedup vs baseline: 1.0398x; 1.0201x over previous
//
#include <hip/hip_runtime.h>
#include <hip/hip_bf16.h>
#include <math.h>

#define B_ 32
#define S_ 128
#define L_ 1024
#define D_ 1024

typedef unsigned short u16;
typedef __attribute__((ext_vector_type(8))) __bf16 bf16x8;
typedef __attribute__((ext_vector_type(4))) float f32x4;

__device__ __forceinline__ float bf2f(u16 u) {
    return __uint_as_float(((unsigned)u) << 16);
}
__device__ __forceinline__ u16 f2bf(float f) {
    unsigned u = __float_as_uint(f);
    u += 0x7FFF + ((u >> 16) & 1);
    return (u16)(u >> 16);
}
__device__ __forceinline__ float gelu_tanh(float x) {
    float x3 = x * x * x;
    float t = tanhf(0.7978845608028654f * (x + 0.044715f * x3));
    return 0.5f * x * (1.0f + t);
}
__device__ __forceinline__ float sigmoidf(float x) {
    return 1.0f / (1.0f + expf(-x));
}
__device__ __forceinline__ void gld16(const void* g, void* l) {
    __builtin_amdgcn_global_load_lds((const __attribute__((address_space(1))) void*)g,
                                     (__attribute__((address_space(3))) void*)l, 16, 0, 0);
}

// ---------------- K0: S4D SSM kernel ---------------------------------------
__global__ __launch_bounds__(256) void k_ssmk(
        const float* __restrict__ log_dt, const float* __restrict__ Alr,
        const float* __restrict__ Aim, const float* __restrict__ Cr,
        const float* __restrict__ Ci, float* __restrict__ Kt) {
    int tid = blockIdx.x * 256 + threadIdx.x;
    int d = tid & (D_ - 1);
    int j = tid >> 10;
    float dt = expf(log_dt[d]);
    float acc = 0.f;
    #pragma unroll
    for (int n = 0; n < 4; ++n) {
        float ar = -expf(Alr[d * 4 + n]);
        float ai = Aim[d * 4 + n];
        float wr = ar * dt, wi = ai * dt;
        float ew = expf(wr);
        float sw, cw; sincosf(wi, &sw, &cw);
        float ur = ew * cw - 1.0f, ui = ew * sw;
        float inv = 1.0f / (ar * ar + ai * ai);
        float bdr = (ur * ar + ui * ai) * inv;
        float bdi = (ui * ar - ur * ai) * inv;
        float cr = Cr[d * 4 + n], ci = Ci[d * 4 + n];
        float cbr = cr * bdr - ci * bdi;
        float cbi = cr * bdi + ci * bdr;
        float ej = expf(wr * (float)j);
        float sj, cj; sincosf(wi * (float)j, &sj, &cj);
        acc += 2.0f * ej * (cbr * cj - cbi * sj);
    }
    Kt[j * D_ + d] = acc;
}

// ---------------- zero rowstat (aliases Kt, runs after conv) ---------------
__global__ __launch_bounds__(256) void k_zero(float* __restrict__ p) {
    int tid = blockIdx.x * 256 + threadIdx.x;   // 16384 threads x float4
    *(float4*)&p[tid * 4] = make_float4(0.f, 0.f, 0.f, 0.f);
}

// ---------------- c1[s]=sum gam_k Wd[k,s]; c2[s]=sum bet_k Wd[k,s]+bd[s] ---
__global__ __launch_bounds__(256) void k_c12(
        const float* __restrict__ Wd, const float* __restrict__ gam,
        const float* __restrict__ bet, const float* __restrict__ bd,
        float* __restrict__ c12) {
    int s = blockIdx.x;
    int t = threadIdx.x;
    float a1 = 0.f, a2 = 0.f;
    #pragma unroll
    for (int it = 0; it < 4; ++it) {
        int k = it * 256 + t;
        float w = Wd[(size_t)k * 128 + s];
        a1 += gam[k] * w;
        a2 += bet[k] * w;
    }
    #pragma unroll
    for (int off = 32; off > 0; off >>= 1) {
        a1 += __shfl_down(a1, off);
        a2 += __shfl_down(a2, off);
    }
    __shared__ float r1[4], r2[4];
    int wid = t >> 6, lane = t & 63;
    if (lane == 0) { r1[wid] = a1; r2[wid] = a2; }
    __syncthreads();
    if (t == 0) {
        c12[s] = r1[0] + r1[1] + r1[2] + r1[3];
        c12[128 + s] = r2[0] + r2[1] + r2[2] + r2[3] + bd[s];
    }
}

// ---------------- transpose+cast (+optional row scale): f32[R][C]->bf16[C][R]
__global__ __launch_bounds__(256) void k_tcast(
        const float* __restrict__ src0, u16* __restrict__ dst0, int R, int C,
        const float* __restrict__ rowscale) {
    __shared__ float tile[64][65];
    const float* src = src0 + (size_t)blockIdx.z * R * C;
    u16* dst = dst0 + (size_t)blockIdx.z * R * C;
    int c0 = blockIdx.x * 64;
    int r0 = blockIdx.y * 64;
    int t = threadIdx.x;
    #pragma unroll
    for (int p = 0; p < 4; ++p) {
        int fid = p * 256 + t;
        int rr = fid >> 4, cc = (fid & 15) * 4;
        float4 v = *(const float4*)&src[(size_t)(r0 + rr) * C + c0 + cc];
        float sc = rowscale ? rowscale[r0 + rr] : 1.0f;
        tile[rr][cc + 0] = v.x * sc; tile[rr][cc + 1] = v.y * sc;
        tile[rr][cc + 2] = v.z * sc; tile[rr][cc + 3] = v.w * sc;
    }
    __syncthreads();
    #pragma unroll
    for (int p = 0; p < 4; ++p) {
        int fid = p * 256 + t;
        int rr = fid >> 4, cc = (fid & 15) * 4;
        ushort4 o;
        o.x = f2bf(tile[cc + 0][rr]);
        o.y = f2bf(tile[cc + 1][rr]);
        o.z = f2bf(tile[cc + 2][rr]);
        o.w = f2bf(tile[cc + 3][rr]);
        *(ushort4*)&dst[(size_t)(c0 + rr) * R + r0 + cc] = o;
    }
}

// ---------------- K1: encoder MFMA ------------------------------------------
__global__ __launch_bounds__(256) void k_enc_mfma(
        const u16* __restrict__ xb, const u16* __restrict__ WeT,
        const float* __restrict__ be, u16* __restrict__ hb) {
    __shared__ u16 As[128 * 128];
    __shared__ u16 Bs[128 * 128];
    int t = threadIdx.x;
    int lane = t & 63, wid = t >> 6;
    int wr = wid & 1, wc = wid >> 1;
    int orig = blockIdx.x;
    int wgid = (orig & 7) * 256 + (orig >> 3);
    int m0 = (wgid >> 3) * 128;
    int e0 = (wgid & 7) * 128;

    #pragma unroll
    for (int c = 0; c < 8; ++c) {
        int ch = wid * 8 + c;
        int r = ch * 4 + (lane >> 4);
        int g = (lane & 15) ^ (r & 15);
        gld16(&xb[(size_t)(m0 + r) * 128 + g * 8], &As[ch * 512]);
        gld16(&WeT[(size_t)(e0 + r) * 128 + g * 8], &Bs[ch * 512]);
    }
    int co4[4];
    #pragma unroll
    for (int kh = 0; kh < 4; ++kh)
        co4[kh] = ((((lane >> 4) + kh * 4) ^ (lane & 15)) * 8);
    int arow[4], brow[4];
    #pragma unroll
    for (int i = 0; i < 4; ++i) arow[i] = (wr * 64 + i * 16 + (lane & 15)) * 128;
    #pragma unroll
    for (int q = 0; q < 4; ++q) brow[q] = (wc * 64 + q * 16 + (lane & 15)) * 128;

    __syncthreads();
    f32x4 acc[4][4] = {};
    #pragma unroll
    for (int kh = 0; kh < 4; ++kh) {
        bf16x8 af[4], bfr[4];
        #pragma unroll
        for (int i = 0; i < 4; ++i) af[i] = *(const bf16x8*)&As[arow[i] + co4[kh]];
        #pragma unroll
        for (int q = 0; q < 4; ++q) bfr[q] = *(const bf16x8*)&Bs[brow[q] + co4[kh]];
        __builtin_amdgcn_s_setprio(1);
        #pragma unroll
        for (int i = 0; i < 4; ++i)
            #pragma unroll
            for (int q = 0; q < 4; ++q)
                acc[i][q] = __builtin_amdgcn_mfma_f32_16x16x32_bf16(af[i], bfr[q], acc[i][q], 0, 0, 0);
        __builtin_amdgcn_s_setprio(0);
    }
    #pragma unroll
    for (int q = 0; q < 4; ++q) {
        int e = e0 + wc * 64 + q * 16 + (lane & 15);
        float bias = be[e];
        #pragma unroll
        for (int i = 0; i < 4; ++i) {
            #pragma unroll
            for (int r = 0; r < 4; ++r) {
                int m = m0 + wr * 64 + i * 16 + (lane >> 4) * 4 + r;
                hb[(size_t)m * 1024 + e] = f2bf(acc[i][q][r] + bias);
            }
        }
    }
}

// ---------------- K2: causal 64-tap conv + D*skip + GELU -------------------
__global__ __launch_bounds__(256) void k_conv(
        const u16* __restrict__ hb, const float* __restrict__ Kt,
        const float* __restrict__ Dv, u16* __restrict__ yg) {
    __shared__ float hs[128][64];
    int b = blockIdx.z;
    int l0 = blockIdx.y * 64;
    int d0 = blockIdx.x * 64;
    int t = threadIdx.x;
    int dl = t & 63, lg = t >> 6;
    #pragma unroll
    for (int p = 0; p < 8; ++p) {
        int fid = p * 256 + t;
        int r = fid >> 4, c4 = fid & 15;
        int l = l0 - 64 + r;
        float4 v = make_float4(0.f, 0.f, 0.f, 0.f);
        if (l >= 0) {
            ushort4 u = *(const ushort4*)&hb[((size_t)b * 1024 + l) * 1024 + d0 + c4 * 4];
            v = make_float4(bf2f(u.x), bf2f(u.y), bf2f(u.z), bf2f(u.w));
        }
        *(float4*)&hs[r][c4 * 4] = v;
    }
    float kr[64];
    #pragma unroll
    for (int j = 0; j < 64; ++j) kr[j] = Kt[j * 1024 + d0 + dl];
    float Dd = Dv[d0 + dl];
    __syncthreads();
    float acc[16] = {};
    int rbase = lg * 16 + 1;
    #pragma unroll
    for (int s = 0; s < 15; ++s) {
        float hv = hs[rbase + s][dl];
        #pragma unroll
        for (int i = 0; i <= 14; ++i)
            if (i <= s) acc[i] = fmaf(kr[i + 63 - s], hv, acc[i]);
    }
    #pragma unroll
    for (int s = 15; s < 64; ++s) {
        float hv = hs[rbase + s][dl];
        #pragma unroll
        for (int i = 0; i < 16; ++i)
            acc[i] = fmaf(kr[i + 63 - s], hv, acc[i]);
    }
    #pragma unroll
    for (int s = 64; s < 79; ++s) {
        float hv = hs[rbase + s][dl];
        #pragma unroll
        for (int i = 1; i < 16; ++i)
            if (i >= s - 63) acc[i] = fmaf(kr[i + 63 - s], hv, acc[i]);
    }
    #pragma unroll
    for (int i = 0; i < 16; ++i) {
        int l = l0 + lg * 16 + i;
        float z = hs[64 + lg * 16 + i][dl];
        float y = acc[i] + Dd * z;
        yg[((size_t)b * 1024 + l) * 1024 + d0 + dl] = f2bf(gelu_tanh(y));
    }
}

// ---------------- K3: GLU GEMM 256x256, read-once frags + staged epilogue --
// Main loop identical to r8 (proven 151us). Epilogue: stage GLU output in LDS
// f32 tile per 64-row chunk, cooperative ushort8-coalesced hb RMW, and
// accumulate per-row sum/sumsq partials -> rowstat atomics (for LN fold).
__global__ __launch_bounds__(512, 2) void k_glu256(
        const u16* __restrict__ yg, const u16* __restrict__ WgT,
        const float* __restrict__ bg, u16* __restrict__ hb,
        float* __restrict__ rowS) {
    __shared__ __align__(16) u16 S[65536];
    int t = threadIdx.x;
    int lane = t & 63, wid = t >> 6;
    int wr = wid >> 2, wc = wid & 3;

    int orig = blockIdx.x;
    int wgid = (orig & 7) * 128 + (orig >> 3);   // bijective (1024 % 8 == 0)
    int m0 = (wgid >> 3) * 256;
    int p0g = (wgid & 7) * 128;

    int gofs = (((lane & 7) ^ ((lane >> 3) & 7)) * 8);
    int ch0 = wid * 2, ch1 = ch0 + 1;
    int dst0 = ch0 * 512 + lane * 8;
    int dst1 = ch1 * 512 + lane * 8;
    int gmA[2][2], gmB[2][2];
    #pragma unroll
    for (int h = 0; h < 2; ++h) {
        #pragma unroll
        for (int j = 0; j < 2; ++j) {
            int ch = ch0 + j;
            gmA[h][j] = m0 + (ch >> 3) * 128 + h * 64 + (ch & 7) * 8 + (lane >> 3);
            int r = (ch >> 2) * 64 + h * 32 + (ch & 3) * 8 + (lane >> 3);
            gmB[h][j] = ((r >> 4) & 1) * 1024 + p0g + (((r >> 5) << 4) | (r & 15));
        }
    }
    int co[2];
    co[0] = (((lane >> 4) + 0) ^ (lane & 7)) * 8;
    co[1] = (((lane >> 4) + 4) ^ (lane & 7)) * 8;
    int arow[4], brow[2];
    #pragma unroll
    for (int i = 0; i < 4; ++i) arow[i] = (wr * 64 + i * 16 + (lane & 15)) * 64;
    #pragma unroll
    for (int q = 0; q < 2; ++q) brow[q] = (wc * 32 + q * 16 + (lane & 15)) * 64;

#define GLD_A(H, BUF, K0) { u16* d_ = &S[((BUF) * 2 + (H)) * 8192]; \
    gld16(&yg[(size_t)gmA[H][0] * 1024 + (K0) + gofs], d_ + dst0); \
    gld16(&yg[(size_t)gmA[H][1] * 1024 + (K0) + gofs], d_ + dst1); }
#define GLD_B(H, BUF, K0) { u16* d_ = &S[32768 + ((BUF) * 2 + (H)) * 8192]; \
    gld16(&WgT[(size_t)gmB[H][0] * 1024 + (K0) + gofs], d_ + dst0); \
    gld16(&WgT[(size_t)gmB[H][1] * 1024 + (K0) + gofs], d_ + dst1); }

#define RD_AH(MS) { const u16* Ar_ = &S[(cbuf * 2 + (MS)) * 8192]; \
    _Pragma("unroll") for (int i = 0; i < 4; ++i) { \
        a_[i][0] = *(const bf16x8*)&Ar_[arow[i] + co[0]]; \
        a_[i][1] = *(const bf16x8*)&Ar_[arow[i] + co[1]]; } }
#define RD_BH(NS, BB) { const u16* Br_ = &S[32768 + (cbuf * 2 + (NS)) * 8192]; \
    _Pragma("unroll") for (int q = 0; q < 2; ++q) { \
        BB[q][0] = *(const bf16x8*)&Br_[brow[q] + co[0]]; \
        BB[q][1] = *(const bf16x8*)&Br_[brow[q] + co[1]]; } }
#define MFMA16(MS, NS, BB) { __builtin_amdgcn_s_setprio(1); \
    _Pragma("unroll") for (int i = 0; i < 4; ++i) \
        _Pragma("unroll") for (int q = 0; q < 2; ++q) { \
            acc[(MS) * 4 + i][(NS) * 2 + q] = __builtin_amdgcn_mfma_f32_16x16x32_bf16( \
                a_[i][0], BB[q][0], acc[(MS) * 4 + i][(NS) * 2 + q], 0, 0, 0); \
            acc[(MS) * 4 + i][(NS) * 2 + q] = __builtin_amdgcn_mfma_f32_16x16x32_bf16( \
                a_[i][1], BB[q][1], acc[(MS) * 4 + i][(NS) * 2 + q], 0, 0, 0); } \
    __builtin_amdgcn_s_setprio(0); }
#define BAR() { __builtin_amdgcn_s_barrier(); __builtin_amdgcn_sched_barrier(0); }

    f32x4 acc[8][4] = {};
    bf16x8 a_[4][2], b0_[2][2], b1_[2][2];

    GLD_A(0, 0, 0); GLD_B(0, 0, 0); GLD_B(1, 0, 0); GLD_A(1, 0, 0);
    GLD_A(0, 1, 64); GLD_B(0, 1, 64);

    for (int kt = 0; kt < 15; ++kt) {
        int cbuf = kt & 1, nbuf = cbuf ^ 1;
        int k1 = (kt + 1) * 64, k2 = (kt + 2) * 64;
        asm volatile("s_waitcnt vmcnt(4)" ::: "memory");
        BAR();
        RD_BH(0, b0_); RD_BH(1, b1_); RD_AH(0);
        GLD_B(1, nbuf, k1);
        MFMA16(0, 0, b0_);
        BAR();
        GLD_A(1, nbuf, k1);
        MFMA16(0, 1, b1_);
        BAR();
        RD_AH(1);
        if (kt < 14) GLD_A(0, cbuf, k2);
        MFMA16(1, 0, b0_);
        BAR();
        if (kt < 14) GLD_B(0, cbuf, k2);
        MFMA16(1, 1, b1_);
    }
    {
        int cbuf = 1;
        asm volatile("s_waitcnt vmcnt(0)" ::: "memory");
        BAR();
        RD_BH(0, b0_); RD_BH(1, b1_); RD_AH(0);
        MFMA16(0, 0, b0_);
        MFMA16(0, 1, b1_);
        RD_AH(1);
        MFMA16(1, 0, b0_);
        MFMA16(1, 1, b1_);
    }
#undef GLD_A
#undef GLD_B
#undef RD_AH
#undef RD_BH
#undef MFMA16
#undef BAR

    // ---- epilogue: 4 chunks of 64 rows; stage f32 in LDS, coalesced RMW ----
    float* Ts = (float*)S;   // [64][132] f32 = 33792 B
    int erow = t >> 3;                 // 0..63
    int ecg = (t & 7) * 16;            // col group 0..112
    #pragma unroll
    for (int chunk = 0; chunk < 4; ++chunk) {
        __syncthreads();
        if (wr == (chunk >> 1)) {
            #pragma unroll
            for (int ii = 0; ii < 4; ++ii) {
                int i = (chunk & 1) * 4 + ii;
                #pragma unroll
                for (int pb = 0; pb < 2; ++pb) {
                    int col = (wc * 2 + pb) * 16 + (lane & 15);
                    float b1v = bg[p0g + col];
                    float b2v = bg[1024 + p0g + col];
                    #pragma unroll
                    for (int r = 0; r < 4; ++r) {
                        int rloc = ii * 16 + (lane >> 4) * 4 + r;
                        float g1 = acc[i][pb * 2][r] + b1v;
                        float g2 = acc[i][pb * 2 + 1][r] + b2v;
                        Ts[rloc * 132 + col] = g1 * sigmoidf(g2);
                    }
                }
            }
        }
        __syncthreads();
        int gm = m0 + chunk * 64 + erow;
        size_t gbase = (size_t)gm * 1024 + p0g + ecg;
        float rs1 = 0.f, rs2 = 0.f;
        #pragma unroll
        for (int h = 0; h < 2; ++h) {
            uint4 hv = *(uint4*)&hb[gbase + h * 8];
            u16* hu = (u16*)&hv;
            #pragma unroll
            for (int e = 0; e < 8; ++e) {
                float v = bf2f(hu[e]) + Ts[erow * 132 + ecg + h * 8 + e];
                rs1 += v;
                rs2 += v * v;
                hu[e] = f2bf(v);
            }
            *(uint4*)&hb[gbase + h * 8] = hv;
        }
        rs1 += __shfl_xor(rs1, 1); rs2 += __shfl_xor(rs2, 1);
        rs1 += __shfl_xor(rs1, 2); rs2 += __shfl_xor(rs2, 2);
        rs1 += __shfl_xor(rs1, 4); rs2 += __shfl_xor(rs2, 4);
        if ((lane & 7) == 0) {
            atomicAdd(&rowS[gm], rs1);
            atomicAdd(&rowS[32768 + gm], rs2);
        }
    }
}

// ---------------- K5: decoder GEMM + LN fold + transpose store -------------
// out[m,s] = rstd_m*G[m,s] - mu_m*rstd_m*c1[s] + c2[s],  G = hb_raw @ (gam.*Wd)
__global__ __launch_bounds__(256) void k_dec_mfma(
        const u16* __restrict__ hb, const u16* __restrict__ WdT,
        const float* __restrict__ rowS, const float* __restrict__ c12,
        float* __restrict__ out) {
    __shared__ __align__(16) char smem[66560];
    u16* As = (u16*)smem;
    u16* Bs = (u16*)(smem + 32768);
    float* Ts = (float*)smem;
    float* muL = (float*)(smem + 65536);          // 128 f32
    float* rsL = (float*)(smem + 65536 + 512);    // 128 f32
    int t = threadIdx.x;
    int lane = t & 63, wid = t >> 6;
    int wr = wid & 1, wc = wid >> 1;
    int m0 = blockIdx.x * 128;
    int bb = m0 >> 10, l0 = m0 & 1023;

    if (t < 128) {
        float s1 = rowS[m0 + t];
        float s2 = rowS[32768 + m0 + t];
        float mu = s1 * (1.0f / 1024.0f);
        float var = s2 * (1.0f / 1024.0f) - mu * mu;
        muL[t] = mu;
        rsL[t] = rsqrtf(var + 1e-5f);
    }

    int gsrc = (((lane & 7) ^ (lane >> 3)) * 8);
    int rr4[4];
    #pragma unroll
    for (int c = 0; c < 4; ++c) rr4[c] = (wid * 4 + c) * 8 + (lane >> 3);
    int co[2];
    co[0] = (((lane >> 4) + 0) ^ (lane & 7)) * 8;
    co[1] = (((lane >> 4) + 4) ^ (lane & 7)) * 8;
    int arow[4], brow[4];
    #pragma unroll
    for (int i = 0; i < 4; ++i) arow[i] = (wr * 64 + i * 16 + (lane & 15)) * 64;
    #pragma unroll
    for (int q = 0; q < 4; ++q) brow[q] = (wc * 64 + q * 16 + (lane & 15)) * 64;

    f32x4 acc[4][4] = {};
    #pragma unroll
    for (int c = 0; c < 4; ++c) {
        int ch = wid * 4 + c;
        gld16(&hb[(size_t)(m0 + rr4[c]) * 1024 + gsrc], &As[0 * 8192 + ch * 512]);
        gld16(&WdT[(size_t)rr4[c] * 1024 + gsrc], &Bs[0 * 8192 + ch * 512]);
    }
    __syncthreads();
    int cur = 0;
    for (int kt = 0; kt < 16; ++kt) {
        if (kt < 15) {
            int k0 = (kt + 1) * 64;
            #pragma unroll
            for (int c = 0; c < 4; ++c) {
                int ch = wid * 4 + c;
                gld16(&hb[(size_t)(m0 + rr4[c]) * 1024 + k0 + gsrc], &As[(cur ^ 1) * 8192 + ch * 512]);
                gld16(&WdT[(size_t)rr4[c] * 1024 + k0 + gsrc], &Bs[(cur ^ 1) * 8192 + ch * 512]);
            }
        }
        #pragma unroll
        for (int kh = 0; kh < 2; ++kh) {
            bf16x8 af[4], bfr[4];
            #pragma unroll
            for (int i = 0; i < 4; ++i) af[i] = *(const bf16x8*)&As[cur * 8192 + arow[i] + co[kh]];
            #pragma unroll
            for (int q = 0; q < 4; ++q) bfr[q] = *(const bf16x8*)&Bs[cur * 8192 + brow[q] + co[kh]];
            __builtin_amdgcn_s_setprio(1);
            #pragma unroll
            for (int i = 0; i < 4; ++i)
                #pragma unroll
                for (int q = 0; q < 4; ++q)
                    acc[i][q] = __builtin_amdgcn_mfma_f32_16x16x32_bf16(af[i], bfr[q], acc[i][q], 0, 0, 0);
            __builtin_amdgcn_s_setprio(0);
        }
        __syncthreads();
        cur ^= 1;
    }
    __syncthreads();
    #pragma unroll
    for (int ro = 0; ro < 2; ++ro) {
        if (wc == ro) {
            #pragma unroll
            for (int i = 0; i < 4; ++i)
                #pragma unroll
                for (int q = 0; q < 4; ++q) {
                    int sl = q * 16 + (lane & 15);
                    float c1v = c12[ro * 64 + sl];
                    float c2v = c12[128 + ro * 64 + sl];
                    #pragma unroll
                    for (int r = 0; r < 4; ++r) {
                        int ml = wr * 64 + i * 16 + (lane >> 4) * 4 + r;
                        float rst = rsL[ml];
                        Ts[sl * 132 + ml] = rst * acc[i][q][r] - muL[ml] * rst * c1v + c2v;
                    }
                }
        }
        __syncthreads();
        #pragma unroll
        for (int p = 0; p < 8; ++p) {
            int fid = p * 256 + t;
            int sl = fid >> 5, c = (fid & 31) * 4;
            float4 v = *(const float4*)&Ts[sl * 132 + c];
            *(float4*)&out[(size_t)bb * 131072 + (size_t)(ro * 64 + sl) * 1024 + l0 + c] = v;
        }
        __syncthreads();
    }
}

extern "C" void kernel_launch(void* const* d_in, const int* in_sizes, int n_in,
                              void* d_out, int out_size, void* d_ws, size_t ws_size,
                              hipStream_t stream) {
    (void)in_sizes; (void)n_in; (void)out_size; (void)ws_size;
    const float* x   = (const float*)d_in[0];
    const float* We  = (const float*)d_in[1];
    const float* be  = (const float*)d_in[2];
    const float* ldt = (const float*)d_in[3];
    const float* Alr = (const float*)d_in[4];
    const float* Aim = (const float*)d_in[5];
    const float* Cr  = (const float*)d_in[6];
    const float* Ci  = (const float*)d_in[7];
    const float* Dv  = (const float*)d_in[8];
    const float* Wg  = (const float*)d_in[9];
    const float* bg  = (const float*)d_in[10];
    const float* gam = (const float*)d_in[11];
    const float* bet = (const float*)d_in[12];
    const float* Wd  = (const float*)d_in[13];
    const float* bd  = (const float*)d_in[14];
    float* out = (float*)d_out;

    u16* hb = (u16*)d_ws;                       // 64 MiB
    u16* yg = hb + 33554432ull;                 // 64 MiB
    float* Kt = (float*)(yg + 33554432ull);     // 256 KB (rowstat alias after conv)
    u16* WgT = (u16*)(Kt + 65536);              // 4 MiB
    u16* WdT = WgT + 2097152ull;                // 256 KB (gamma-scaled W2T)
    u16* WeT = WdT + 131072ull;                 // 256 KB (c12 alias after enc)
    u16* xb  = yg;                              // alias: xb dead before conv writes yg
    float* rowS = Kt;                           // alias: Kt dead after conv
    float* c12  = (float*)WeT;                  // alias: WeT dead after enc

    k_tcast<<<dim3(32, 16, 1), 256, 0, stream>>>(Wg, WgT, 1024, 2048, nullptr);
    k_tcast<<<dim3(2, 16, 1), 256, 0, stream>>>(Wd, WdT, 1024, 128, gam);
    k_tcast<<<dim3(16, 2, 1), 256, 0, stream>>>(We, WeT, 128, 1024, nullptr);
    k_tcast<<<dim3(16, 2, 32), 256, 0, stream>>>(x, xb, 128, 1024, nullptr);
    k_ssmk<<<256, 256, 0, stream>>>(ldt, Alr, Aim, Cr, Ci, Kt);
    k_enc_mfma<<<2048, 256, 0, stream>>>(xb, WeT, be, hb);
    k_conv<<<dim3(16, 16, 32), 256, 0, stream>>>(hb, Kt, Dv, yg);
    k_c12<<<128, 256, 0, stream>>>(Wd, gam, bet, bd, c12);
    k_zero<<<64, 256, 0, stream>>>(rowS);
    k_glu256<<<1024, 512, 0, stream>>>(yg, WgT, bg, hb, rowS);
    k_dec_mfma<<<256, 256, 0, stream>>>(hb, WdT, rowS, c12, out);
}

// Round 10
// 328.388 us; speedup vs baseline: 1.0646x; 1.0239x over previous
//
#include <hip/hip_runtime.h>
#include <hip/hip_bf16.h>
#include <math.h>

#define B_ 32
#define S_ 128
#define L_ 1024
#define D_ 1024

typedef unsigned short u16;
typedef __attribute__((ext_vector_type(8))) __bf16 bf16x8;
typedef __attribute__((ext_vector_type(8))) short short8;
typedef __attribute__((ext_vector_type(4))) float f32x4;

__device__ __forceinline__ float bf2f(u16 u) {
    return __uint_as_float(((unsigned)u) << 16);
}
__device__ __forceinline__ u16 f2bf(float f) {
    unsigned u = __float_as_uint(f);
    u += 0x7FFF + ((u >> 16) & 1);
    return (u16)(u >> 16);
}
__device__ __forceinline__ float gelu_tanh(float x) {
    float x3 = x * x * x;
    float t = tanhf(0.7978845608028654f * (x + 0.044715f * x3));
    return 0.5f * x * (1.0f + t);
}
__device__ __forceinline__ float sigmoidf(float x) {
    return 1.0f / (1.0f + expf(-x));
}
__device__ __forceinline__ void gld16(const void* g, void* l) {
    __builtin_amdgcn_global_load_lds((const __attribute__((address_space(1))) void*)g,
                                     (__attribute__((address_space(3))) void*)l, 16, 0, 0);
}

// ---------------- K0: S4D SSM kernel ---------------------------------------
__global__ __launch_bounds__(256) void k_ssmk(
        const float* __restrict__ log_dt, const float* __restrict__ Alr,
        const float* __restrict__ Aim, const float* __restrict__ Cr,
        const float* __restrict__ Ci, float* __restrict__ Kt) {
    int tid = blockIdx.x * 256 + threadIdx.x;
    int d = tid & (D_ - 1);
    int j = tid >> 10;
    float dt = expf(log_dt[d]);
    float acc = 0.f;
    #pragma unroll
    for (int n = 0; n < 4; ++n) {
        float ar = -expf(Alr[d * 4 + n]);
        float ai = Aim[d * 4 + n];
        float wr = ar * dt, wi = ai * dt;
        float ew = expf(wr);
        float sw, cw; sincosf(wi, &sw, &cw);
        float ur = ew * cw - 1.0f, ui = ew * sw;
        float inv = 1.0f / (ar * ar + ai * ai);
        float bdr = (ur * ar + ui * ai) * inv;
        float bdi = (ui * ar - ur * ai) * inv;
        float cr = Cr[d * 4 + n], ci = Ci[d * 4 + n];
        float cbr = cr * bdr - ci * bdi;
        float cbi = cr * bdi + ci * bdr;
        float ej = expf(wr * (float)j);
        float sj, cj; sincosf(wi * (float)j, &sj, &cj);
        acc += 2.0f * ej * (cbr * cj - cbi * sj);
    }
    Kt[j * D_ + d] = acc;
}

// ---------------- c1[s]=sum gam_k Wd[k,s]; c2[s]=sum bet_k Wd[k,s]+bd[s] ---
__global__ __launch_bounds__(256) void k_c12(
        const float* __restrict__ Wd, const float* __restrict__ gam,
        const float* __restrict__ bet, const float* __restrict__ bd,
        float* __restrict__ c12) {
    int s = blockIdx.x;
    int t = threadIdx.x;
    float a1 = 0.f, a2 = 0.f;
    #pragma unroll
    for (int it = 0; it < 4; ++it) {
        int k = it * 256 + t;
        float w = Wd[(size_t)k * 128 + s];
        a1 += gam[k] * w;
        a2 += bet[k] * w;
    }
    #pragma unroll
    for (int off = 32; off > 0; off >>= 1) {
        a1 += __shfl_down(a1, off);
        a2 += __shfl_down(a2, off);
    }
    __shared__ float r1[4], r2[4];
    int wid = t >> 6, lane = t & 63;
    if (lane == 0) { r1[wid] = a1; r2[wid] = a2; }
    __syncthreads();
    if (t == 0) {
        c12[s] = r1[0] + r1[1] + r1[2] + r1[3];
        c12[128 + s] = r2[0] + r2[1] + r2[2] + r2[3] + bd[s];
    }
}

// ---------------- transpose+cast (+optional row scale): f32[R][C]->bf16[C][R]
__global__ __launch_bounds__(256) void k_tcast(
        const float* __restrict__ src0, u16* __restrict__ dst0, int R, int C,
        const float* __restrict__ rowscale) {
    __shared__ float tile[64][65];
    const float* src = src0 + (size_t)blockIdx.z * R * C;
    u16* dst = dst0 + (size_t)blockIdx.z * R * C;
    int c0 = blockIdx.x * 64;
    int r0 = blockIdx.y * 64;
    int t = threadIdx.x;
    #pragma unroll
    for (int p = 0; p < 4; ++p) {
        int fid = p * 256 + t;
        int rr = fid >> 4, cc = (fid & 15) * 4;
        float4 v = *(const float4*)&src[(size_t)(r0 + rr) * C + c0 + cc];
        float sc = rowscale ? rowscale[r0 + rr] : 1.0f;
        tile[rr][cc + 0] = v.x * sc; tile[rr][cc + 1] = v.y * sc;
        tile[rr][cc + 2] = v.z * sc; tile[rr][cc + 3] = v.w * sc;
    }
    __syncthreads();
    #pragma unroll
    for (int p = 0; p < 4; ++p) {
        int fid = p * 256 + t;
        int rr = fid >> 4, cc = (fid & 15) * 4;
        ushort4 o;
        o.x = f2bf(tile[cc + 0][rr]);
        o.y = f2bf(tile[cc + 1][rr]);
        o.z = f2bf(tile[cc + 2][rr]);
        o.w = f2bf(tile[cc + 3][rr]);
        *(ushort4*)&dst[(size_t)(c0 + rr) * R + r0 + cc] = o;
    }
}

// ---------------- K1: encoder MFMA ------------------------------------------
__global__ __launch_bounds__(256) void k_enc_mfma(
        const u16* __restrict__ xb, const u16* __restrict__ WeT,
        const float* __restrict__ be, u16* __restrict__ hb) {
    __shared__ u16 As[128 * 128];
    __shared__ u16 Bs[128 * 128];
    int t = threadIdx.x;
    int lane = t & 63, wid = t >> 6;
    int wr = wid & 1, wc = wid >> 1;
    int orig = blockIdx.x;
    int wgid = (orig & 7) * 256 + (orig >> 3);
    int m0 = (wgid >> 3) * 128;
    int e0 = (wgid & 7) * 128;

    #pragma unroll
    for (int c = 0; c < 8; ++c) {
        int ch = wid * 8 + c;
        int r = ch * 4 + (lane >> 4);
        int g = (lane & 15) ^ (r & 15);
        gld16(&xb[(size_t)(m0 + r) * 128 + g * 8], &As[ch * 512]);
        gld16(&WeT[(size_t)(e0 + r) * 128 + g * 8], &Bs[ch * 512]);
    }
    int co4[4];
    #pragma unroll
    for (int kh = 0; kh < 4; ++kh)
        co4[kh] = ((((lane >> 4) + kh * 4) ^ (lane & 15)) * 8);
    int arow[4], brow[4];
    #pragma unroll
    for (int i = 0; i < 4; ++i) arow[i] = (wr * 64 + i * 16 + (lane & 15)) * 128;
    #pragma unroll
    for (int q = 0; q < 4; ++q) brow[q] = (wc * 64 + q * 16 + (lane & 15)) * 128;

    __syncthreads();
    f32x4 acc[4][4] = {};
    #pragma unroll
    for (int kh = 0; kh < 4; ++kh) {
        bf16x8 af[4], bfr[4];
        #pragma unroll
        for (int i = 0; i < 4; ++i) af[i] = *(const bf16x8*)&As[arow[i] + co4[kh]];
        #pragma unroll
        for (int q = 0; q < 4; ++q) bfr[q] = *(const bf16x8*)&Bs[brow[q] + co4[kh]];
        __builtin_amdgcn_s_setprio(1);
        #pragma unroll
        for (int i = 0; i < 4; ++i)
            #pragma unroll
            for (int q = 0; q < 4; ++q)
                acc[i][q] = __builtin_amdgcn_mfma_f32_16x16x32_bf16(af[i], bfr[q], acc[i][q], 0, 0, 0);
        __builtin_amdgcn_s_setprio(0);
    }
    #pragma unroll
    for (int q = 0; q < 4; ++q) {
        int e = e0 + wc * 64 + q * 16 + (lane & 15);
        float bias = be[e];
        #pragma unroll
        for (int i = 0; i < 4; ++i) {
            #pragma unroll
            for (int r = 0; r < 4; ++r) {
                int m = m0 + wr * 64 + i * 16 + (lane >> 4) * 4 + r;
                hb[(size_t)m * 1024 + e] = f2bf(acc[i][q][r] + bias);
            }
        }
    }
}

// ---------------- K2: conv, halo-free ring sweep ---------------------------
// 512 blocks (16 d-tiles x 32 b); each sweeps l=0..1023 in 16 steps of 64.
// LDS ring hs[128][68] (row = l & 127); each hb element loaded exactly once.
__global__ __launch_bounds__(256) void k_conv(
        const u16* __restrict__ hb, const float* __restrict__ Kt,
        const float* __restrict__ Dv, u16* __restrict__ yg) {
    __shared__ float hs[128][68];
    int b = blockIdx.y;
    int d0 = blockIdx.x * 64;
    int t = threadIdx.x;
    int dl = t & 63, lg = t >> 6;
    // zero halo rows 64..127 (= l mod 128 of l in [-64,-1])
    {
        int r = 64 + (t >> 2), cg0 = (t & 3) * 16;
        #pragma unroll
        for (int j = 0; j < 4; ++j)
            *(float4*)&hs[r][cg0 + j * 4] = make_float4(0.f, 0.f, 0.f, 0.f);
    }
    float kr[64];
    #pragma unroll
    for (int j = 0; j < 64; ++j) kr[j] = Kt[j * 1024 + d0 + dl];
    float Dd = Dv[d0 + dl];
    int lr = t >> 2, cg = (t & 3) * 16;
    for (int it = 0; it < 16; ++it) {
        int l0 = it * 64;
        // load chunk rows l0..l0+63 into ring rows (l & 127)
        {
            int l = l0 + lr;
            int row = l & 127;
            const u16* src = &hb[((size_t)b * 1024 + l) * 1024 + d0 + cg];
            #pragma unroll
            for (int h = 0; h < 2; ++h) {
                ushort4 u0 = *(const ushort4*)&src[h * 8];
                ushort4 u1 = *(const ushort4*)&src[h * 8 + 4];
                *(float4*)&hs[row][cg + h * 8] =
                    make_float4(bf2f(u0.x), bf2f(u0.y), bf2f(u0.z), bf2f(u0.w));
                *(float4*)&hs[row][cg + h * 8 + 4] =
                    make_float4(bf2f(u1.x), bf2f(u1.y), bf2f(u1.z), bf2f(u1.w));
            }
        }
        __syncthreads();
        float acc[16] = {};
        int rb = l0 + 65 + lg * 16;   // ring row of s=0 (l0-63 == l0+65 mod 128)
        #pragma unroll
        for (int s = 0; s < 15; ++s) {
            float hv = hs[(rb + s) & 127][dl];
            #pragma unroll
            for (int i = 0; i <= 14; ++i)
                if (i <= s) acc[i] = fmaf(kr[i + 63 - s], hv, acc[i]);
        }
        #pragma unroll
        for (int s = 15; s < 64; ++s) {
            float hv = hs[(rb + s) & 127][dl];
            #pragma unroll
            for (int i = 0; i < 16; ++i)
                acc[i] = fmaf(kr[i + 63 - s], hv, acc[i]);
        }
        #pragma unroll
        for (int s = 64; s < 79; ++s) {
            float hv = hs[(rb + s) & 127][dl];
            #pragma unroll
            for (int i = 1; i < 16; ++i)
                if (i >= s - 63) acc[i] = fmaf(kr[i + 63 - s], hv, acc[i]);
        }
        #pragma unroll
        for (int i = 0; i < 16; ++i) {
            int l = l0 + lg * 16 + i;
            float z = hs[l & 127][dl];
            float y = acc[i] + Dd * z;
            yg[((size_t)b * 1024 + l) * 1024 + d0 + dl] = f2bf(gelu_tanh(y));
        }
        __syncthreads();   // protect ring rows until next chunk overwrites
    }
}

// ---------------- K3: GLU GEMM 256x256, read-once frags (r8-proven) --------
__global__ __launch_bounds__(512, 2) void k_glu256(
        const u16* __restrict__ yg, const u16* __restrict__ WgT,
        const float* __restrict__ bg, u16* __restrict__ hb) {
    __shared__ u16 S[65536];   // A: [buf*2+h]*8192, B: 32768 + [buf*2+h]*8192
    int t = threadIdx.x;
    int lane = t & 63, wid = t >> 6;
    int wr = wid >> 2, wc = wid & 3;

    int orig = blockIdx.x;
    int wgid = (orig & 7) * 128 + (orig >> 3);   // bijective (1024 % 8 == 0)
    int m0 = (wgid >> 3) * 256;
    int p0g = (wgid & 7) * 128;

    int gofs = (((lane & 7) ^ ((lane >> 3) & 7)) * 8);
    int ch0 = wid * 2, ch1 = ch0 + 1;
    int dst0 = ch0 * 512 + lane * 8;
    int dst1 = ch1 * 512 + lane * 8;
    int gmA[2][2], gmB[2][2];
    #pragma unroll
    for (int h = 0; h < 2; ++h) {
        #pragma unroll
        for (int j = 0; j < 2; ++j) {
            int ch = ch0 + j;
            gmA[h][j] = m0 + (ch >> 3) * 128 + h * 64 + (ch & 7) * 8 + (lane >> 3);
            int r = (ch >> 2) * 64 + h * 32 + (ch & 3) * 8 + (lane >> 3);
            gmB[h][j] = ((r >> 4) & 1) * 1024 + p0g + (((r >> 5) << 4) | (r & 15));
        }
    }
    int co[2];
    co[0] = (((lane >> 4) + 0) ^ (lane & 7)) * 8;
    co[1] = (((lane >> 4) + 4) ^ (lane & 7)) * 8;
    int arow[4], brow[2];
    #pragma unroll
    for (int i = 0; i < 4; ++i) arow[i] = (wr * 64 + i * 16 + (lane & 15)) * 64;
    #pragma unroll
    for (int q = 0; q < 2; ++q) brow[q] = (wc * 32 + q * 16 + (lane & 15)) * 64;

#define GLD_A(H, BUF, K0) { u16* d_ = &S[((BUF) * 2 + (H)) * 8192]; \
    gld16(&yg[(size_t)gmA[H][0] * 1024 + (K0) + gofs], d_ + dst0); \
    gld16(&yg[(size_t)gmA[H][1] * 1024 + (K0) + gofs], d_ + dst1); }
#define GLD_B(H, BUF, K0) { u16* d_ = &S[32768 + ((BUF) * 2 + (H)) * 8192]; \
    gld16(&WgT[(size_t)gmB[H][0] * 1024 + (K0) + gofs], d_ + dst0); \
    gld16(&WgT[(size_t)gmB[H][1] * 1024 + (K0) + gofs], d_ + dst1); }

#define RD_AH(MS) { const u16* Ar_ = &S[(cbuf * 2 + (MS)) * 8192]; \
    _Pragma("unroll") for (int i = 0; i < 4; ++i) { \
        a_[i][0] = *(const bf16x8*)&Ar_[arow[i] + co[0]]; \
        a_[i][1] = *(const bf16x8*)&Ar_[arow[i] + co[1]]; } }
#define RD_BH(NS, BB) { const u16* Br_ = &S[32768 + (cbuf * 2 + (NS)) * 8192]; \
    _Pragma("unroll") for (int q = 0; q < 2; ++q) { \
        BB[q][0] = *(const bf16x8*)&Br_[brow[q] + co[0]]; \
        BB[q][1] = *(const bf16x8*)&Br_[brow[q] + co[1]]; } }
#define MFMA16(MS, NS, BB) { __builtin_amdgcn_s_setprio(1); \
    _Pragma("unroll") for (int i = 0; i < 4; ++i) \
        _Pragma("unroll") for (int q = 0; q < 2; ++q) { \
            acc[(MS) * 4 + i][(NS) * 2 + q] = __builtin_amdgcn_mfma_f32_16x16x32_bf16( \
                a_[i][0], BB[q][0], acc[(MS) * 4 + i][(NS) * 2 + q], 0, 0, 0); \
            acc[(MS) * 4 + i][(NS) * 2 + q] = __builtin_amdgcn_mfma_f32_16x16x32_bf16( \
                a_[i][1], BB[q][1], acc[(MS) * 4 + i][(NS) * 2 + q], 0, 0, 0); } \
    __builtin_amdgcn_s_setprio(0); }
#define BAR() { __builtin_amdgcn_s_barrier(); __builtin_amdgcn_sched_barrier(0); }

    f32x4 acc[8][4] = {};
    bf16x8 a_[4][2], b0_[2][2], b1_[2][2];

    GLD_A(0, 0, 0); GLD_B(0, 0, 0); GLD_B(1, 0, 0); GLD_A(1, 0, 0);
    GLD_A(0, 1, 64); GLD_B(0, 1, 64);

    for (int kt = 0; kt < 15; ++kt) {
        int cbuf = kt & 1, nbuf = cbuf ^ 1;
        int k1 = (kt + 1) * 64, k2 = (kt + 2) * 64;
        asm volatile("s_waitcnt vmcnt(4)" ::: "memory");
        BAR();
        RD_BH(0, b0_); RD_BH(1, b1_); RD_AH(0);
        GLD_B(1, nbuf, k1);
        MFMA16(0, 0, b0_);
        BAR();
        GLD_A(1, nbuf, k1);
        MFMA16(0, 1, b1_);
        BAR();
        RD_AH(1);
        if (kt < 14) GLD_A(0, cbuf, k2);
        MFMA16(1, 0, b0_);
        BAR();
        if (kt < 14) GLD_B(0, cbuf, k2);
        MFMA16(1, 1, b1_);
    }
    {
        int cbuf = 1;
        asm volatile("s_waitcnt vmcnt(0)" ::: "memory");
        BAR();
        RD_BH(0, b0_); RD_BH(1, b1_); RD_AH(0);
        MFMA16(0, 0, b0_);
        MFMA16(0, 1, b1_);
        RD_AH(1);
        MFMA16(1, 0, b0_);
        MFMA16(1, 1, b1_);
    }
#undef GLD_A
#undef GLD_B
#undef RD_AH
#undef RD_BH
#undef MFMA16
#undef BAR

    // epilogue: GLU activation + residual in-place (r8-proven form)
    #pragma unroll
    for (int i = 0; i < 8; ++i) {
        #pragma unroll
        for (int pb = 0; pb < 2; ++pb) {
            int col = p0g + (wc * 2 + pb) * 16 + (lane & 15);
            float b1v = bg[col];
            float b2v = bg[1024 + col];
            #pragma unroll
            for (int r = 0; r < 4; ++r) {
                int m = m0 + wr * 128 + i * 16 + (lane >> 4) * 4 + r;
                size_t idx = (size_t)m * 1024 + col;
                float g1 = acc[i][pb * 2][r] + b1v;
                float g2 = acc[i][pb * 2 + 1][r] + b2v;
                hb[idx] = f2bf(bf2f(hb[idx]) + g1 * sigmoidf(g2));
            }
        }
    }
}

// ---------------- K5: decoder GEMM + in-loop LN stats + fold ---------------
// out[m,s] = rstd_m*G[m,s] - mu_m*rstd_m*c1[s] + c2[s],  G = hb_raw @ (gam.*Wd)
// Row stats from A-fragments: per lane, granules (lane>>4 + 4kh)^(lane&7)
// tile the 64-k range exactly once across lane>>4 in {0..3} -> shfl_xor(16,32)
// reduce gives exact row sums over all 1024 k.
__global__ __launch_bounds__(256) void k_dec_mfma(
        const u16* __restrict__ hb, const u16* __restrict__ WdT,
        const float* __restrict__ c12, float* __restrict__ out) {
    __shared__ __align__(16) char smem[66560];
    u16* As = (u16*)smem;
    u16* Bs = (u16*)(smem + 32768);
    float* Ts = (float*)smem;
    float* muL = (float*)(smem + 65536);          // 128 f32
    float* rsL = (float*)(smem + 65536 + 512);    // 128 f32
    int t = threadIdx.x;
    int lane = t & 63, wid = t >> 6;
    int wr = wid & 1, wc = wid >> 1;
    int m0 = blockIdx.x * 128;
    int bb = m0 >> 10, l0 = m0 & 1023;

    int gsrc = (((lane & 7) ^ (lane >> 3)) * 8);
    int rr4[4];
    #pragma unroll
    for (int c = 0; c < 4; ++c) rr4[c] = (wid * 4 + c) * 8 + (lane >> 3);
    int co[2];
    co[0] = (((lane >> 4) + 0) ^ (lane & 7)) * 8;
    co[1] = (((lane >> 4) + 4) ^ (lane & 7)) * 8;
    int arow[4], brow[4];
    #pragma unroll
    for (int i = 0; i < 4; ++i) arow[i] = (wr * 64 + i * 16 + (lane & 15)) * 64;
    #pragma unroll
    for (int q = 0; q < 4; ++q) brow[q] = (wc * 64 + q * 16 + (lane & 15)) * 64;

    f32x4 acc[4][4] = {};
    float s1[4] = {}, s2[4] = {};
    #pragma unroll
    for (int c = 0; c < 4; ++c) {
        int ch = wid * 4 + c;
        gld16(&hb[(size_t)(m0 + rr4[c]) * 1024 + gsrc], &As[0 * 8192 + ch * 512]);
        gld16(&WdT[(size_t)rr4[c] * 1024 + gsrc], &Bs[0 * 8192 + ch * 512]);
    }
    __syncthreads();
    int cur = 0;
    for (int kt = 0; kt < 16; ++kt) {
        if (kt < 15) {
            int k0 = (kt + 1) * 64;
            #pragma unroll
            for (int c = 0; c < 4; ++c) {
                int ch = wid * 4 + c;
                gld16(&hb[(size_t)(m0 + rr4[c]) * 1024 + k0 + gsrc], &As[(cur ^ 1) * 8192 + ch * 512]);
                gld16(&WdT[(size_t)rr4[c] * 1024 + k0 + gsrc], &Bs[(cur ^ 1) * 8192 + ch * 512]);
            }
        }
        #pragma unroll
        for (int kh = 0; kh < 2; ++kh) {
            bf16x8 af[4], bfr[4];
            #pragma unroll
            for (int i = 0; i < 4; ++i) af[i] = *(const bf16x8*)&As[cur * 8192 + arow[i] + co[kh]];
            #pragma unroll
            for (int q = 0; q < 4; ++q) bfr[q] = *(const bf16x8*)&Bs[cur * 8192 + brow[q] + co[kh]];
            if (wid < 2) {
                #pragma unroll
                for (int i = 0; i < 4; ++i) {
                    short8 sa = *(short8*)&af[i];
                    #pragma unroll
                    for (int e = 0; e < 8; ++e) {
                        float v = bf2f((u16)sa[e]);
                        s1[i] += v;
                        s2[i] = fmaf(v, v, s2[i]);
                    }
                }
            }
            __builtin_amdgcn_s_setprio(1);
            #pragma unroll
            for (int i = 0; i < 4; ++i)
                #pragma unroll
                for (int q = 0; q < 4; ++q)
                    acc[i][q] = __builtin_amdgcn_mfma_f32_16x16x32_bf16(af[i], bfr[q], acc[i][q], 0, 0, 0);
            __builtin_amdgcn_s_setprio(0);
        }
        __syncthreads();
        cur ^= 1;
    }
    // reduce stats (waves 0,1 hold all 128 rows) and publish to LDS
    if (wid < 2) {
        #pragma unroll
        for (int i = 0; i < 4; ++i) {
            s1[i] += __shfl_xor(s1[i], 16);
            s2[i] += __shfl_xor(s2[i], 16);
            s1[i] += __shfl_xor(s1[i], 32);
            s2[i] += __shfl_xor(s2[i], 32);
            if (lane < 16) {
                int ml = wr * 64 + i * 16 + lane;
                float mu = s1[i] * (1.0f / 1024.0f);
                float var = s2[i] * (1.0f / 1024.0f) - mu * mu;
                muL[ml] = mu;
                rsL[ml] = rsqrtf(var + 1e-5f);
            }
        }
    }
    __syncthreads();
    #pragma unroll
    for (int ro = 0; ro < 2; ++ro) {
        if (wc == ro) {
            #pragma unroll
            for (int i = 0; i < 4; ++i)
                #pragma unroll
                for (int q = 0; q < 4; ++q) {
                    int sl = q * 16 + (lane & 15);
                    float c1v = c12[ro * 64 + sl];
                    float c2v = c12[128 + ro * 64 + sl];
                    #pragma unroll
                    for (int r = 0; r < 4; ++r) {
                        int ml = wr * 64 + i * 16 + (lane >> 4) * 4 + r;
                        float rst = rsL[ml];
                        Ts[sl * 132 + ml] = rst * acc[i][q][r] - muL[ml] * rst * c1v + c2v;
                    }
                }
        }
        __syncthreads();
        #pragma unroll
        for (int p = 0; p < 8; ++p) {
            int fid = p * 256 + t;
            int sl = fid >> 5, c = (fid & 31) * 4;
            float4 v = *(const float4*)&Ts[sl * 132 + c];
            *(float4*)&out[(size_t)bb * 131072 + (size_t)(ro * 64 + sl) * 1024 + l0 + c] = v;
        }
        __syncthreads();
    }
}

extern "C" void kernel_launch(void* const* d_in, const int* in_sizes, int n_in,
                              void* d_out, int out_size, void* d_ws, size_t ws_size,
                              hipStream_t stream) {
    (void)in_sizes; (void)n_in; (void)out_size; (void)ws_size;
    const float* x   = (const float*)d_in[0];
    const float* We  = (const float*)d_in[1];
    const float* be  = (const float*)d_in[2];
    const float* ldt = (const float*)d_in[3];
    const float* Alr = (const float*)d_in[4];
    const float* Aim = (const float*)d_in[5];
    const float* Cr  = (const float*)d_in[6];
    const float* Ci  = (const float*)d_in[7];
    const float* Dv  = (const float*)d_in[8];
    const float* Wg  = (const float*)d_in[9];
    const float* bg  = (const float*)d_in[10];
    const float* gam = (const float*)d_in[11];
    const float* bet = (const float*)d_in[12];
    const float* Wd  = (const float*)d_in[13];
    const float* bd  = (const float*)d_in[14];
    float* out = (float*)d_out;

    u16* hb = (u16*)d_ws;                       // 64 MiB
    u16* yg = hb + 33554432ull;                 // 64 MiB
    float* Kt = (float*)(yg + 33554432ull);     // 256 KB
    u16* WgT = (u16*)(Kt + 65536);              // 4 MiB
    u16* WdT = WgT + 2097152ull;                // 256 KB (gamma-scaled WdT)
    u16* WeT = WdT + 131072ull;                 // 256 KB (c12 alias after enc)
    u16* xb  = yg;                              // alias: xb dead before conv writes yg
    float* c12  = (float*)WeT;                  // alias: WeT dead after enc

    k_tcast<<<dim3(32, 16, 1), 256, 0, stream>>>(Wg, WgT, 1024, 2048, nullptr);
    k_tcast<<<dim3(2, 16, 1), 256, 0, stream>>>(Wd, WdT, 1024, 128, gam);
    k_tcast<<<dim3(16, 2, 1), 256, 0, stream>>>(We, WeT, 128, 1024, nullptr);
    k_tcast<<<dim3(16, 2, 32), 256, 0, stream>>>(x, xb, 128, 1024, nullptr);
    k_ssmk<<<256, 256, 0, stream>>>(ldt, Alr, Aim, Cr, Ci, Kt);
    k_enc_mfma<<<2048, 256, 0, stream>>>(xb, WeT, be, hb);
    k_conv<<<dim3(16, 32), 256, 0, stream>>>(hb, Kt, Dv, yg);
    k_c12<<<128, 256, 0, stream>>>(Wd, gam, bet, bd, c12);
    k_glu256<<<1024, 512, 0, stream>>>(yg, WgT, bg, hb);
    k_dec_mfma<<<256, 256, 0, stream>>>(hb, WdT, c12, out);
}